// Round 2
// baseline (651.777 us; speedup 1.0000x reference)
//
#include <hip/hip_runtime.h>
#include <hip/hip_bf16.h>

#define B_ 4
#define I_ 512
#define J_ 512
#define C_ 512
#define P_ 128
#define H_ 4
#define D_ 32
#define HD_ 128
#define EPS_ 1e-5f
#define INF_ 1.0e9f

__device__ __forceinline__ float dot4(float4 a, float4 b) {
    return a.x * b.x + a.y * b.y + a.z * b.z + a.w * b.w;
}

// DPP cross-lane add on the VALU pipe (no DS). CTRL compile-time.
template<int CTRL>
__device__ __forceinline__ float dppadd(float x) {
    int xi = __float_as_int(x);
    int yi = __builtin_amdgcn_update_dpp(xi, xi, CTRL, 0xf, 0xf, false);
    return x + __int_as_float(yi);
}
// full sum across a 16-lane group, result in every lane
__device__ __forceinline__ float red16(float x) {
    x = dppadd<0xB1>(x);   // quad_perm xor1
    x = dppadd<0x4E>(x);   // quad_perm xor2
    x = dppadd<0x141>(x);  // row_half_mirror (pairs 8-groups)
    x = dppadd<0x140>(x);  // row_mirror (pairs 16-halves)
    return x;
}

// ---------------------------------------------------------------------------
// K0: fold LN gamma/beta into pair->head weights.
// gwf[p][h] = g_p * w[p][h]  (h 0-3 = w_pb, 4-7 = w_pg)
// AB[h]   = sum_p g_p w[p][h]   (h 0..7)
// AB[8+h] = sum_p b_p w[p][h]
// grid: 1 block, 128 threads
// ---------------------------------------------------------------------------
__global__ void k_fold(const float* __restrict__ lng, const float* __restrict__ lnb,
                       const float* __restrict__ wpb, const float* __restrict__ wpg,
                       float* __restrict__ gwf, float* __restrict__ AB)
{
    __shared__ float sg[P_ * 8], sb[P_ * 8];
    const int p = threadIdx.x;
    const float g = lng[p], b = lnb[p];
#pragma unroll
    for (int h = 0; h < 4; h++) {
        const float wb = wpb[p * 4 + h], wg = wpg[p * 4 + h];
        gwf[p * 8 + h]     = g * wb;
        gwf[p * 8 + 4 + h] = g * wg;
        sg[p * 8 + h]      = g * wb;
        sg[p * 8 + 4 + h]  = g * wg;
        sb[p * 8 + h]      = b * wb;
        sb[p * 8 + 4 + h]  = b * wg;
    }
    __syncthreads();
    if (p < 16) {
        const float* src = (p < 8) ? sg : sb;
        const int h = p & 7;
        float a = 0.0f;
        for (int q = 0; q < P_; q++) a += src[q * 8 + h];
        AB[p] = a;
    }
}

// ---------------------------------------------------------------------------
// K1: LayerNorm of node_embed_i and node_embed_j. One wave per row.
// ---------------------------------------------------------------------------
__global__ __launch_bounds__(256) void k_ln_nodes(
    const float* __restrict__ xi, const float* __restrict__ xj,
    const float* __restrict__ g_i, const float* __restrict__ b_i,
    const float* __restrict__ g_j, const float* __restrict__ b_j,
    float* __restrict__ ni, float* __restrict__ nj)
{
    const int which = blockIdx.y;
    const float* x  = which ? xj  : xi;
    const float* gg = which ? g_j : g_i;
    const float* bb = which ? b_j : b_i;
    float* o        = which ? nj  : ni;

    const int row  = blockIdx.x * 4 + (threadIdx.x >> 6);
    const int lane = threadIdx.x & 63;

    const float* xr = x + (size_t)row * C_ + lane * 8;
    float4 v0 = *(const float4*)xr;
    float4 v1 = *(const float4*)(xr + 4);

    float s  = v0.x + v0.y + v0.z + v0.w + v1.x + v1.y + v1.z + v1.w;
    float sq = v0.x*v0.x + v0.y*v0.y + v0.z*v0.z + v0.w*v0.w
             + v1.x*v1.x + v1.y*v1.y + v1.z*v1.z + v1.w*v1.w;
#pragma unroll
    for (int m = 1; m <= 32; m <<= 1) {
        s  += __shfl_xor(s, m);
        sq += __shfl_xor(sq, m);
    }
    const float mean = s * (1.0f / C_);
    const float var  = sq * (1.0f / C_) - mean * mean;
    const float rstd = rsqrtf(var + EPS_);

    float4 ga  = *(const float4*)(gg + lane * 8);
    float4 gb  = *(const float4*)(gg + lane * 8 + 4);
    float4 ba  = *(const float4*)(bb + lane * 8);
    float4 bb4 = *(const float4*)(bb + lane * 8 + 4);

    float4 r0, r1;
    r0.x = (v0.x - mean) * rstd * ga.x + ba.x;
    r0.y = (v0.y - mean) * rstd * ga.y + ba.y;
    r0.z = (v0.z - mean) * rstd * ga.z + ba.z;
    r0.w = (v0.w - mean) * rstd * ga.w + ba.w;
    r1.x = (v1.x - mean) * rstd * gb.x + bb4.x;
    r1.y = (v1.y - mean) * rstd * gb.y + bb4.y;
    r1.z = (v1.z - mean) * rstd * gb.z + bb4.z;
    r1.w = (v1.w - mean) * rstd * gb.w + bb4.w;

    float* orow = o + (size_t)row * C_ + lane * 8;
    *(float4*)orow       = r0;
    *(float4*)(orow + 4) = r1;
}

// ---------------------------------------------------------------------------
// K2: pair path, restructured. 16 lanes per (b,i,j) row; lane owns 8
// consecutive p's. Single pass accumulates s, sq, S0..7 (folded-weight dots);
// reduction via 4 DPP steps on the VALU pipe (zero DS traffic). LN closed
// form applied from (mean, rstd, A_h, B_h).
// grid: (B*I*J/16), block: 256 (16 rows per block)
// ---------------------------------------------------------------------------
#define ACC_STEP(E, XE) { \
    s += (XE); sq = fmaf((XE), (XE), sq); \
    S0 = fmaf((XE), wa##E.x, S0); S1 = fmaf((XE), wa##E.y, S1); \
    S2 = fmaf((XE), wa##E.z, S2); S3 = fmaf((XE), wa##E.w, S3); \
    S4 = fmaf((XE), wb##E.x, S4); S5 = fmaf((XE), wb##E.y, S5); \
    S6 = fmaf((XE), wb##E.z, S6); S7 = fmaf((XE), wb##E.w, S7); }

__global__ __launch_bounds__(256) void k_pair_bias(
    const float* __restrict__ pair, const int* __restrict__ pmask,
    const float* __restrict__ gwf, const float* __restrict__ AB,
    float* __restrict__ bias)
{
    const int tid = threadIdx.x;
    const int sub = tid & 15;
    const int grp = tid >> 4;                   // 16 groups per block
    const int row = blockIdx.x * 16 + grp;      // [0, B*I*J)

    // x: this lane's 8 elements of the row
    const float* xr = pair + (size_t)row * P_ + sub * 8;
    const float4 x0 = *(const float4*)xr;
    const float4 x1 = *(const float4*)(xr + 4);

    // folded weights for this lane's 8 p-rows: gwf[sub*8+e][0..7]
    const float4* wp = (const float4*)(gwf) + sub * 16;
    const float4 wa0 = wp[0],  wb0 = wp[1],  wa1 = wp[2],  wb1 = wp[3];
    const float4 wa2 = wp[4],  wb2 = wp[5],  wa3 = wp[6],  wb3 = wp[7];
    const float4 wa4 = wp[8],  wb4 = wp[9],  wa5 = wp[10], wb5 = wp[11];
    const float4 wa6 = wp[12], wb6 = wp[13], wa7 = wp[14], wb7 = wp[15];

    float s = 0.0f, sq = 0.0f;
    float S0 = 0, S1 = 0, S2 = 0, S3 = 0, S4 = 0, S5 = 0, S6 = 0, S7 = 0;
    ACC_STEP(0, x0.x) ACC_STEP(1, x0.y) ACC_STEP(2, x0.z) ACC_STEP(3, x0.w)
    ACC_STEP(4, x1.x) ACC_STEP(5, x1.y) ACC_STEP(6, x1.z) ACC_STEP(7, x1.w)

    // 16-lane reduction, all on VALU pipe
    s  = red16(s);  sq = red16(sq);
    S0 = red16(S0); S1 = red16(S1); S2 = red16(S2); S3 = red16(S3);
    S4 = red16(S4); S5 = red16(S5); S6 = red16(S6); S7 = red16(S7);

    if (sub < 4) {
        const float mean = s * (1.0f / P_);
        const float rstd = rsqrtf(sq * (1.0f / P_) - mean * mean + EPS_);
        const float mr   = mean * rstd;

        const float Sl = (sub == 0) ? S0 : (sub == 1) ? S1 : (sub == 2) ? S2 : S3;
        const float Sg = (sub == 0) ? S4 : (sub == 1) ? S5 : (sub == 2) ? S6 : S7;
        const float Al = AB[sub],     Bl = AB[8 + sub];
        const float Ag = AB[4 + sub], Bg = AB[12 + sub];

        const float left = rstd * Sl - mr * Al + Bl;
        const float glog = rstd * Sg - mr * Ag + Bg;
        const float gate = 1.0f / (1.0f + __expf(-glog));
        const float mb   = INF_ * ((float)pmask[row] - 1.0f);

        const int j = row & (J_ - 1);
        const int i = (row >> 9) & (I_ - 1);
        const int b = row >> 18;
        bias[(((size_t)(b * H_ + sub) * I_ + i) << 9) + j] = left * gate + mb;
    }
}

// ---------------------------------------------------------------------------
// K3: projections q,k,v,g. blockIdx.y selects the matrix. 16-row A tile in
// LDS (broadcast reads); weights streamed from L2.
// grid: (B*I/16, 4), block: 256
// ---------------------------------------------------------------------------
__global__ __launch_bounds__(256) void k_proj(
    const float* __restrict__ ni, const float* __restrict__ nj,
    const float* __restrict__ wq, const float* __restrict__ wk,
    const float* __restrict__ wv, const float* __restrict__ wg,
    const float* __restrict__ bg,
    float* __restrict__ q_ws, float* __restrict__ k_ws,
    float* __restrict__ v_ws, float* __restrict__ g_ws)
{
    __shared__ float s_src[16 * 512];
    const int y    = blockIdx.y;
    const int tid  = threadIdx.x;
    const int base = blockIdx.x * 16;   // row in [0, B*I)

    const float* src = (y == 0 || y == 3) ? ni : nj;
    const float* W   = (y == 0) ? wq : (y == 1) ? wk : (y == 2) ? wv : wg;

    const float* sg = src + (size_t)base * C_;
#pragma unroll
    for (int rep = 0; rep < 8; rep++) {
        const int flat = rep * 1024 + tid * 4;
        *(float4*)&s_src[flat] = *(const float4*)(sg + flat);
    }
    __syncthreads();

    const int col = tid & 127;
    const int r0  = (tid >> 7) * 8;
    float acc[8] = {0, 0, 0, 0, 0, 0, 0, 0};

#pragma unroll 4
    for (int c = 0; c < C_; c++) {
        const float w = W[c * HD_ + col];
#pragma unroll
        for (int r = 0; r < 8; r++) acc[r] += s_src[(r0 + r) * 512 + c] * w;
    }

    if (y == 3) {
        const float bgc = bg[col];
#pragma unroll
        for (int r = 0; r < 8; r++) {
            const float gv = 1.0f / (1.0f + __expf(-(acc[r] + bgc)));
            g_ws[(size_t)(base + r0 + r) * HD_ + col] = gv;
        }
    } else {
        const int b  = base >> 9;
        const int i0 = base & 511;
        const int h  = col >> 5, d = col & 31;
        const float scale = (y == 0) ? 0.17677669529663689f : 1.0f;  // 1/sqrt(32)
        float* dst = (y == 0) ? q_ws : (y == 1) ? k_ws : v_ws;
#pragma unroll
        for (int r = 0; r < 8; r++)
            dst[((size_t)(b * H_ + h) * 512 + i0 + r0 + r) * D_ + d] = acc[r] * scale;
    }
}

// ---------------------------------------------------------------------------
// K4: attention for one (b,h) and a 16-row i tile.
// grid: (I/16, B*H), block: 256
// ---------------------------------------------------------------------------
__global__ __launch_bounds__(256) void k_attn(
    const float* __restrict__ q_ws, const float* __restrict__ k_ws,
    const float* __restrict__ v_ws, const float* __restrict__ bias,
    float* __restrict__ o_ws)
{
    __shared__ float s_a[16 * 520];
    const int tid = threadIdx.x;
    const int bh  = blockIdx.y;          // b*H + h
    const int b   = bh >> 2, h = bh & 3;
    const int i0  = blockIdx.x * 16;
    const int i   = tid >> 4;
    const int l16 = tid & 15;

    const float* qrow = q_ws + ((size_t)bh * I_ + i0 + i) * D_;
    const float4 q0 = *(const float4*)(qrow);
    const float4 q1 = *(const float4*)(qrow + 4);
    const float4 q2 = *(const float4*)(qrow + 8);
    const float4 q3 = *(const float4*)(qrow + 12);
    const float4 q4 = *(const float4*)(qrow + 16);
    const float4 q5 = *(const float4*)(qrow + 20);
    const float4 q6 = *(const float4*)(qrow + 24);
    const float4 q7 = *(const float4*)(qrow + 28);

    float acc[32];
    const float* brow = bias + ((size_t)bh * I_ + i0 + i) * J_;
#pragma unroll
    for (int e = 0; e < 32; e++) acc[e] = brow[l16 + 16 * e];

    const float* kbase = k_ws + (size_t)bh * J_ * D_;
#pragma unroll
    for (int e = 0; e < 32; e++) {
        const float* kp = kbase + (l16 + 16 * e) * D_;
        const float4 k0 = *(const float4*)(kp);
        const float4 k1 = *(const float4*)(kp + 4);
        const float4 k2 = *(const float4*)(kp + 8);
        const float4 k3 = *(const float4*)(kp + 12);
        const float4 k4 = *(const float4*)(kp + 16);
        const float4 k5 = *(const float4*)(kp + 20);
        const float4 k6 = *(const float4*)(kp + 24);
        const float4 k7 = *(const float4*)(kp + 28);
        acc[e] += dot4(q0, k0) + dot4(q1, k1) + dot4(q2, k2) + dot4(q3, k3)
                + dot4(q4, k4) + dot4(q5, k5) + dot4(q6, k6) + dot4(q7, k7);
    }

    float mx = acc[0];
#pragma unroll
    for (int e = 1; e < 32; e++) mx = fmaxf(mx, acc[e]);
#pragma unroll
    for (int m = 1; m < 16; m <<= 1) mx = fmaxf(mx, __shfl_xor(mx, m));
    float sum = 0.0f;
#pragma unroll
    for (int e = 0; e < 32; e++) { acc[e] = __expf(acc[e] - mx); sum += acc[e]; }
#pragma unroll
    for (int m = 1; m < 16; m <<= 1) sum += __shfl_xor(sum, m);
#pragma unroll
    for (int e = 0; e < 32; e++) s_a[i * 520 + l16 + 16 * e] = acc[e];
    const float scale = 1.0f / sum;
    __syncthreads();

    const int dg = l16;
    const float* vbase = v_ws + (size_t)bh * J_ * D_ + 2 * dg;
    float o0 = 0.0f, o1 = 0.0f;
#pragma unroll 8
    for (int jj = 0; jj < J_; jj++) {
        const float a = s_a[i * 520 + jj];
        const float2 vv = *(const float2*)(vbase + (size_t)jj * D_);
        o0 += a * vv.x;
        o1 += a * vv.y;
    }
    float* op = o_ws + ((size_t)(b * I_ + i0 + i)) * HD_ + h * D_ + 2 * dg;
    op[0] = o0 * scale;
    op[1] = o1 * scale;
}

// ---------------------------------------------------------------------------
// K5: out = ni + ((o*g) @ wo + bo) * node_mask.
// grid: (B*I/8), block: 256
// ---------------------------------------------------------------------------
__global__ __launch_bounds__(256) void k_out(
    const float* __restrict__ o_ws, const float* __restrict__ g_ws,
    const float* __restrict__ ni, const float* __restrict__ wo,
    const float* __restrict__ bo, const int* __restrict__ nmask,
    float* __restrict__ out)
{
    __shared__ float s_og[8 * 128];
    const int tid  = threadIdx.x;
    const int base = blockIdx.x * 8;     // row in [0, B*I)

#pragma unroll
    for (int rep = 0; rep < 4; rep++) {
        const int flat = rep * 256 + tid;
        s_og[flat] = o_ws[(size_t)base * HD_ + flat] * g_ws[(size_t)base * HD_ + flat];
    }
    __syncthreads();

    const int c0 = tid * 2;
    float a0[8] = {0, 0, 0, 0, 0, 0, 0, 0};
    float a1[8] = {0, 0, 0, 0, 0, 0, 0, 0};

#pragma unroll 4
    for (int hd = 0; hd < HD_; hd++) {
        const float2 w = *(const float2*)(wo + hd * C_ + c0);
#pragma unroll
        for (int r = 0; r < 8; r++) {
            const float v = s_og[r * 128 + hd];
            a0[r] += v * w.x;
            a1[r] += v * w.y;
        }
    }

    const float b0v = bo[c0], b1v = bo[c0 + 1];
#pragma unroll
    for (int r = 0; r < 8; r++) {
        const int row = base + r;
        const float mk = (float)nmask[row];
        const size_t off = (size_t)row * C_ + c0;
        out[off]     = ni[off]     + (a0[r] + b0v) * mk;
        out[off + 1] = ni[off + 1] + (a1[r] + b1v) * mk;
    }
}

// ---------------------------------------------------------------------------
extern "C" void kernel_launch(void* const* d_in, const int* in_sizes, int n_in,
                              void* d_out, int out_size, void* d_ws, size_t ws_size,
                              hipStream_t stream)
{
    const float* node_i = (const float*)d_in[0];
    const float* node_j = (const float*)d_in[1];
    const float* pair   = (const float*)d_in[2];
    const int*   pmask  = (const int*)d_in[3];
    const int*   nmask  = (const int*)d_in[4];
    const float* ln_i_g = (const float*)d_in[5];
    const float* ln_i_b = (const float*)d_in[6];
    const float* ln_j_g = (const float*)d_in[7];
    const float* ln_j_b = (const float*)d_in[8];
    const float* ln_p_g = (const float*)d_in[9];
    const float* ln_p_b = (const float*)d_in[10];
    const float* w_pb   = (const float*)d_in[11];
    const float* w_pg   = (const float*)d_in[12];
    const float* wq     = (const float*)d_in[13];
    const float* wk     = (const float*)d_in[14];
    const float* wv     = (const float*)d_in[15];
    const float* wg     = (const float*)d_in[16];
    const float* bg     = (const float*)d_in[17];
    const float* wo     = (const float*)d_in[18];
    const float* bo     = (const float*)d_in[19];

    float* out = (float*)d_out;
    float* ws  = (float*)d_ws;

    float* ni   = ws;                 // 1,048,576 floats
    float* nj   = ws + 1048576;       // 1,048,576
    float* bias = ws + 2097152;       // 4,194,304  [B,H,I,J]
    float* q_ws = ws + 6291456;       // 262,144
    float* k_ws = ws + 6553600;       // 262,144
    float* v_ws = ws + 6815744;       // 262,144
    float* g_ws = ws + 7077888;       // 262,144
    float* o_ws = ws + 7340032;       // 262,144
    float* gwf  = ws + 7602176;       // 1,024   folded pair weights
    float* AB   = ws + 7603200;       // 16      A[0..7], B[0..7]

    k_fold<<<dim3(1), 128, 0, stream>>>(ln_p_g, ln_p_b, w_pb, w_pg, gwf, AB);
    k_ln_nodes<<<dim3(512, 2), 256, 0, stream>>>(node_i, node_j, ln_i_g, ln_i_b,
                                                 ln_j_g, ln_j_b, ni, nj);
    k_pair_bias<<<dim3(65536), 256, 0, stream>>>(pair, pmask, gwf, AB, bias);
    k_proj<<<dim3(128, 4), 256, 0, stream>>>(ni, nj, wq, wk, wv, wg, bg,
                                             q_ws, k_ws, v_ws, g_ws);
    k_attn<<<dim3(32, 16), 256, 0, stream>>>(q_ws, k_ws, v_ws, bias, o_ws);
    k_out<<<dim3(256), 256, 0, stream>>>(o_ws, g_ws, ni, wo, bo, nmask, out);
}

// Round 3
// 292.397 us; speedup vs baseline: 2.2291x; 2.2291x over previous
//
#include <hip/hip_runtime.h>
#include <hip/hip_bf16.h>

#define B_ 4
#define I_ 512
#define J_ 512
#define C_ 512
#define P_ 128
#define H_ 4
#define D_ 32
#define HD_ 128
#define EPS_ 1e-5f
#define INF_ 1.0e9f

typedef __attribute__((ext_vector_type(8))) short bf16x8;
typedef __attribute__((ext_vector_type(4))) float f32x4;

__device__ __forceinline__ float dot4(float4 a, float4 b) {
    return a.x * b.x + a.y * b.y + a.z * b.z + a.w * b.w;
}

// fp32 -> bf16 (RNE) as raw short
__device__ __forceinline__ short f2bf(float f) {
    unsigned u = __float_as_uint(f);
    u += 0x7fffu + ((u >> 16) & 1u);
    return (short)(u >> 16);
}

// ---------------------------------------------------------------------------
// K0: fold LN gamma into pair->head weights, laid out as MFMA B-fragments.
// B-frag for kstep s, lane l, elem e:  B[k][n] with k = s*32 + (l>>4)*8 + e,
// n = l&15.  n<4 -> w_pb col n; 4<=n<8 -> w_pg col n-4; n>=8 -> 0.
// AB[0..3]=A_left, AB[4..7]=A_gate, AB[8..11]=B_left, AB[12..15]=B_gate
// where A_h = sum_p g_p w_ph, B_h = sum_p b_p w_ph.
// grid: 1 block, 256 threads
// ---------------------------------------------------------------------------
__global__ void k_fold(const float* __restrict__ lng, const float* __restrict__ lnb,
                       const float* __restrict__ wpb, const float* __restrict__ wpg,
                       short* __restrict__ gwfB, float* __restrict__ AB)
{
    const int t = threadIdx.x;
    const int s = t >> 6, lane = t & 63;
    const int c = lane >> 4, n = lane & 15;
#pragma unroll
    for (int e = 0; e < 8; e++) {
        const int p = s * 32 + c * 8 + e;
        const float w = (n < 4) ? wpb[p * 4 + n] : (n < 8) ? wpg[p * 4 + (n - 4)] : 0.0f;
        gwfB[(s * 64 + lane) * 8 + e] = f2bf(lng[p] * w);
    }
    if (t < 16) {
        const int h = t & 7;
        const float* w  = (h < 4) ? wpb : wpg;
        const int col   = h & 3;
        const float* gb = (t < 8) ? lng : lnb;
        float a = 0.0f;
        for (int p = 0; p < P_; p++) a += gb[p] * w[p * 4 + col];
        AB[t] = a;
    }
}

// ---------------------------------------------------------------------------
// K1: LayerNorm of node_embed_i and node_embed_j. One wave per row.
// ---------------------------------------------------------------------------
__global__ __launch_bounds__(256) void k_ln_nodes(
    const float* __restrict__ xi, const float* __restrict__ xj,
    const float* __restrict__ g_i, const float* __restrict__ b_i,
    const float* __restrict__ g_j, const float* __restrict__ b_j,
    float* __restrict__ ni, float* __restrict__ nj)
{
    const int which = blockIdx.y;
    const float* x  = which ? xj  : xi;
    const float* gg = which ? g_j : g_i;
    const float* bb = which ? b_j : b_i;
    float* o        = which ? nj  : ni;

    const int row  = blockIdx.x * 4 + (threadIdx.x >> 6);
    const int lane = threadIdx.x & 63;

    const float* xr = x + (size_t)row * C_ + lane * 8;
    float4 v0 = *(const float4*)xr;
    float4 v1 = *(const float4*)(xr + 4);

    float s  = v0.x + v0.y + v0.z + v0.w + v1.x + v1.y + v1.z + v1.w;
    float sq = v0.x*v0.x + v0.y*v0.y + v0.z*v0.z + v0.w*v0.w
             + v1.x*v1.x + v1.y*v1.y + v1.z*v1.z + v1.w*v1.w;
#pragma unroll
    for (int m = 1; m <= 32; m <<= 1) {
        s  += __shfl_xor(s, m);
        sq += __shfl_xor(sq, m);
    }
    const float mean = s * (1.0f / C_);
    const float var  = sq * (1.0f / C_) - mean * mean;
    const float rstd = rsqrtf(var + EPS_);

    float4 ga  = *(const float4*)(gg + lane * 8);
    float4 gb  = *(const float4*)(gg + lane * 8 + 4);
    float4 ba  = *(const float4*)(bb + lane * 8);
    float4 bb4 = *(const float4*)(bb + lane * 8 + 4);

    float4 r0, r1;
    r0.x = (v0.x - mean) * rstd * ga.x + ba.x;
    r0.y = (v0.y - mean) * rstd * ga.y + ba.y;
    r0.z = (v0.z - mean) * rstd * ga.z + ba.z;
    r0.w = (v0.w - mean) * rstd * ga.w + ba.w;
    r1.x = (v1.x - mean) * rstd * gb.x + bb4.x;
    r1.y = (v1.y - mean) * rstd * gb.y + bb4.y;
    r1.z = (v1.z - mean) * rstd * gb.z + bb4.z;
    r1.w = (v1.w - mean) * rstd * gb.w + bb4.w;

    float* orow = o + (size_t)row * C_ + lane * 8;
    *(float4*)orow       = r0;
    *(float4*)(orow + 4) = r1;
}

// ---------------------------------------------------------------------------
// K2: pair path via MFMA. One wave per 16-row tile (16 consecutive j of one
// (b,i)). A = x rows (bf16-converted), B = folded weights (resident frags).
// s/sq on VALU with 2-lane-hop reduce; epilogue via C-layout
// (col=lane&15=head, row=(lane>>4)*4+reg = j offset)  [m89-verified].
// grid: (B*I*J/16/4), block: 256 (4 waves = 4 tiles)
// ---------------------------------------------------------------------------
__global__ __launch_bounds__(256) void k_pair_bias(
    const float* __restrict__ pair, const int* __restrict__ pmask,
    const short* __restrict__ gwfB, const float* __restrict__ AB,
    float* __restrict__ bias)
{
    const int lane = threadIdx.x & 63;
    const int wid  = threadIdx.x >> 6;
    const int tile = blockIdx.x * 4 + wid;
    const int base = tile * 16;            // flat (b,i,j) row base
    const int r    = lane & 15;            // A row / C col index
    const int c    = lane >> 4;            // k-chunk / C row-group

    // ---- loads (all independent, issue early) ----
    const float* xp = pair + (size_t)(base + r) * P_ + c * 8;
    f32x4 xa[4], xb[4];
#pragma unroll
    for (int s = 0; s < 4; s++) {
        xa[s] = *(const f32x4*)(xp + s * 32);
        xb[s] = *(const f32x4*)(xp + s * 32 + 4);
    }
    bf16x8 bfrag[4];
#pragma unroll
    for (int s = 0; s < 4; s++)
        bfrag[s] = *(const bf16x8*)(gwfB + (s * 64 + lane) * 8);

    const float pm = (float)pmask[base + r];
    const int n4 = r & 3;
    const float Al = AB[n4], Ag = AB[4 + n4], Bl = AB[8 + n4], Bg = AB[12 + n4];

    // ---- per-kstep: convert to bf16, accumulate s/sq, MFMA ----
    f32x4 acc = {0.0f, 0.0f, 0.0f, 0.0f};
    float sum = 0.0f, sq = 0.0f;
#pragma unroll
    for (int s = 0; s < 4; s++) {
        const float e0 = xa[s].x, e1 = xa[s].y, e2 = xa[s].z, e3 = xa[s].w;
        const float e4 = xb[s].x, e5 = xb[s].y, e6 = xb[s].z, e7 = xb[s].w;
        sum += e0 + e1 + e2 + e3 + e4 + e5 + e6 + e7;
        sq = fmaf(e0, e0, sq); sq = fmaf(e1, e1, sq);
        sq = fmaf(e2, e2, sq); sq = fmaf(e3, e3, sq);
        sq = fmaf(e4, e4, sq); sq = fmaf(e5, e5, sq);
        sq = fmaf(e6, e6, sq); sq = fmaf(e7, e7, sq);
        bf16x8 afrag;
        afrag[0] = f2bf(e0); afrag[1] = f2bf(e1);
        afrag[2] = f2bf(e2); afrag[3] = f2bf(e3);
        afrag[4] = f2bf(e4); afrag[5] = f2bf(e5);
        afrag[6] = f2bf(e6); afrag[7] = f2bf(e7);
        acc = __builtin_amdgcn_mfma_f32_16x16x32_bf16(afrag, bfrag[s], acc, 0, 0, 0);
    }

    // ---- row stats: lanes {r, r+16, r+32, r+48} cover row r's 128 elems ----
    sum += __shfl_xor(sum, 16); sum += __shfl_xor(sum, 32);
    sq  += __shfl_xor(sq, 16);  sq  += __shfl_xor(sq, 32);
    const float mean = sum * (1.0f / P_);
    const float rstd = rsqrtf(sq * (1.0f / P_) - mean * mean + EPS_);
    const float mr   = mean * rstd;
    const float mb   = INF_ * (pm - 1.0f);

    // ---- epilogue ----
    const int j0 = base & (J_ - 1);
    const int i  = (base >> 9) & (I_ - 1);
    const int b  = base >> 18;
    float* obase = bias + (((size_t)(b * H_ + n4) * I_ + i) << 9) + j0;

#pragma unroll
    for (int reg = 0; reg < 4; reg++) {
        const int rr = c * 4 + reg;               // C row = local j
        const float rstd_r = __shfl(rstd, rr);    // lane rr holds row rr stats
        const float mr_r   = __shfl(mr, rr);
        const float mb_r   = __shfl(mb, rr);
        const float Sg     = __shfl(acc[reg], lane + 4);  // gate logit lives at col+4
        if (r < 4) {
            const float left = fmaf(rstd_r, acc[reg], fmaf(-mr_r, Al, Bl));
            const float glog = fmaf(rstd_r, Sg,       fmaf(-mr_r, Ag, Bg));
            const float val  = left * (1.0f / (1.0f + __expf(-glog))) + mb_r;
            obase[rr] = val;
        }
    }
}

// ---------------------------------------------------------------------------
// K3: projections q,k,v,g. blockIdx.y selects the matrix. 16-row A tile in
// LDS (broadcast reads); weights streamed from L2.
// grid: (B*I/16, 4), block: 256
// ---------------------------------------------------------------------------
__global__ __launch_bounds__(256) void k_proj(
    const float* __restrict__ ni, const float* __restrict__ nj,
    const float* __restrict__ wq, const float* __restrict__ wk,
    const float* __restrict__ wv, const float* __restrict__ wg,
    const float* __restrict__ bg,
    float* __restrict__ q_ws, float* __restrict__ k_ws,
    float* __restrict__ v_ws, float* __restrict__ g_ws)
{
    __shared__ float s_src[16 * 512];
    const int y    = blockIdx.y;
    const int tid  = threadIdx.x;
    const int base = blockIdx.x * 16;   // row in [0, B*I)

    const float* src = (y == 0 || y == 3) ? ni : nj;
    const float* W   = (y == 0) ? wq : (y == 1) ? wk : (y == 2) ? wv : wg;

    const float* sg = src + (size_t)base * C_;
#pragma unroll
    for (int rep = 0; rep < 8; rep++) {
        const int flat = rep * 1024 + tid * 4;
        *(float4*)&s_src[flat] = *(const float4*)(sg + flat);
    }
    __syncthreads();

    const int col = tid & 127;
    const int r0  = (tid >> 7) * 8;
    float acc[8] = {0, 0, 0, 0, 0, 0, 0, 0};

#pragma unroll 4
    for (int c = 0; c < C_; c++) {
        const float w = W[c * HD_ + col];
#pragma unroll
        for (int r = 0; r < 8; r++) acc[r] += s_src[(r0 + r) * 512 + c] * w;
    }

    if (y == 3) {
        const float bgc = bg[col];
#pragma unroll
        for (int r = 0; r < 8; r++) {
            const float gv = 1.0f / (1.0f + __expf(-(acc[r] + bgc)));
            g_ws[(size_t)(base + r0 + r) * HD_ + col] = gv;
        }
    } else {
        const int b  = base >> 9;
        const int i0 = base & 511;
        const int h  = col >> 5, d = col & 31;
        const float scale = (y == 0) ? 0.17677669529663689f : 1.0f;  // 1/sqrt(32)
        float* dst = (y == 0) ? q_ws : (y == 1) ? k_ws : v_ws;
#pragma unroll
        for (int r = 0; r < 8; r++)
            dst[((size_t)(b * H_ + h) * 512 + i0 + r0 + r) * D_ + d] = acc[r] * scale;
    }
}

// ---------------------------------------------------------------------------
// K4: attention for one (b,h) and a 16-row i tile.
// grid: (I/16, B*H), block: 256
// ---------------------------------------------------------------------------
__global__ __launch_bounds__(256) void k_attn(
    const float* __restrict__ q_ws, const float* __restrict__ k_ws,
    const float* __restrict__ v_ws, const float* __restrict__ bias,
    float* __restrict__ o_ws)
{
    __shared__ float s_a[16 * 520];
    const int tid = threadIdx.x;
    const int bh  = blockIdx.y;          // b*H + h
    const int b   = bh >> 2, h = bh & 3;
    const int i0  = blockIdx.x * 16;
    const int i   = tid >> 4;
    const int l16 = tid & 15;

    const float* qrow = q_ws + ((size_t)bh * I_ + i0 + i) * D_;
    const float4 q0 = *(const float4*)(qrow);
    const float4 q1 = *(const float4*)(qrow + 4);
    const float4 q2 = *(const float4*)(qrow + 8);
    const float4 q3 = *(const float4*)(qrow + 12);
    const float4 q4 = *(const float4*)(qrow + 16);
    const float4 q5 = *(const float4*)(qrow + 20);
    const float4 q6 = *(const float4*)(qrow + 24);
    const float4 q7 = *(const float4*)(qrow + 28);

    float acc[32];
    const float* brow = bias + ((size_t)bh * I_ + i0 + i) * J_;
#pragma unroll
    for (int e = 0; e < 32; e++) acc[e] = brow[l16 + 16 * e];

    const float* kbase = k_ws + (size_t)bh * J_ * D_;
#pragma unroll
    for (int e = 0; e < 32; e++) {
        const float* kp = kbase + (l16 + 16 * e) * D_;
        const float4 k0 = *(const float4*)(kp);
        const float4 k1 = *(const float4*)(kp + 4);
        const float4 k2 = *(const float4*)(kp + 8);
        const float4 k3 = *(const float4*)(kp + 12);
        const float4 k4 = *(const float4*)(kp + 16);
        const float4 k5 = *(const float4*)(kp + 20);
        const float4 k6 = *(const float4*)(kp + 24);
        const float4 k7 = *(const float4*)(kp + 28);
        acc[e] += dot4(q0, k0) + dot4(q1, k1) + dot4(q2, k2) + dot4(q3, k3)
                + dot4(q4, k4) + dot4(q5, k5) + dot4(q6, k6) + dot4(q7, k7);
    }

    float mx = acc[0];
#pragma unroll
    for (int e = 1; e < 32; e++) mx = fmaxf(mx, acc[e]);
#pragma unroll
    for (int m = 1; m < 16; m <<= 1) mx = fmaxf(mx, __shfl_xor(mx, m));
    float sum = 0.0f;
#pragma unroll
    for (int e = 0; e < 32; e++) { acc[e] = __expf(acc[e] - mx); sum += acc[e]; }
#pragma unroll
    for (int m = 1; m < 16; m <<= 1) sum += __shfl_xor(sum, m);
#pragma unroll
    for (int e = 0; e < 32; e++) s_a[i * 520 + l16 + 16 * e] = acc[e];
    const float scale = 1.0f / sum;
    __syncthreads();

    const int dg = l16;
    const float* vbase = v_ws + (size_t)bh * J_ * D_ + 2 * dg;
    float o0 = 0.0f, o1 = 0.0f;
#pragma unroll 8
    for (int jj = 0; jj < J_; jj++) {
        const float a = s_a[i * 520 + jj];
        const float2 vv = *(const float2*)(vbase + (size_t)jj * D_);
        o0 += a * vv.x;
        o1 += a * vv.y;
    }
    float* op = o_ws + ((size_t)(b * I_ + i0 + i)) * HD_ + h * D_ + 2 * dg;
    op[0] = o0 * scale;
    op[1] = o1 * scale;
}

// ---------------------------------------------------------------------------
// K5: out = ni + ((o*g) @ wo + bo) * node_mask.
// grid: (B*I/8), block: 256
// ---------------------------------------------------------------------------
__global__ __launch_bounds__(256) void k_out(
    const float* __restrict__ o_ws, const float* __restrict__ g_ws,
    const float* __restrict__ ni, const float* __restrict__ wo,
    const float* __restrict__ bo, const int* __restrict__ nmask,
    float* __restrict__ out)
{
    __shared__ float s_og[8 * 128];
    const int tid  = threadIdx.x;
    const int base = blockIdx.x * 8;     // row in [0, B*I)

#pragma unroll
    for (int rep = 0; rep < 4; rep++) {
        const int flat = rep * 256 + tid;
        s_og[flat] = o_ws[(size_t)base * HD_ + flat] * g_ws[(size_t)base * HD_ + flat];
    }
    __syncthreads();

    const int c0 = tid * 2;
    float a0[8] = {0, 0, 0, 0, 0, 0, 0, 0};
    float a1[8] = {0, 0, 0, 0, 0, 0, 0, 0};

#pragma unroll 4
    for (int hd = 0; hd < HD_; hd++) {
        const float2 w = *(const float2*)(wo + hd * C_ + c0);
#pragma unroll
        for (int r = 0; r < 8; r++) {
            const float v = s_og[r * 128 + hd];
            a0[r] += v * w.x;
            a1[r] += v * w.y;
        }
    }

    const float b0v = bo[c0], b1v = bo[c0 + 1];
#pragma unroll
    for (int r = 0; r < 8; r++) {
        const int row = base + r;
        const float mk = (float)nmask[row];
        const size_t off = (size_t)row * C_ + c0;
        out[off]     = ni[off]     + (a0[r] + b0v) * mk;
        out[off + 1] = ni[off + 1] + (a1[r] + b1v) * mk;
    }
}

// ---------------------------------------------------------------------------
extern "C" void kernel_launch(void* const* d_in, const int* in_sizes, int n_in,
                              void* d_out, int out_size, void* d_ws, size_t ws_size,
                              hipStream_t stream)
{
    const float* node_i = (const float*)d_in[0];
    const float* node_j = (const float*)d_in[1];
    const float* pair   = (const float*)d_in[2];
    const int*   pmask  = (const int*)d_in[3];
    const int*   nmask  = (const int*)d_in[4];
    const float* ln_i_g = (const float*)d_in[5];
    const float* ln_i_b = (const float*)d_in[6];
    const float* ln_j_g = (const float*)d_in[7];
    const float* ln_j_b = (const float*)d_in[8];
    const float* ln_p_g = (const float*)d_in[9];
    const float* ln_p_b = (const float*)d_in[10];
    const float* w_pb   = (const float*)d_in[11];
    const float* w_pg   = (const float*)d_in[12];
    const float* wq     = (const float*)d_in[13];
    const float* wk     = (const float*)d_in[14];
    const float* wv     = (const float*)d_in[15];
    const float* wg     = (const float*)d_in[16];
    const float* bg     = (const float*)d_in[17];
    const float* wo     = (const float*)d_in[18];
    const float* bo     = (const float*)d_in[19];

    float* out = (float*)d_out;
    float* ws  = (float*)d_ws;

    float* ni   = ws;                 // 1,048,576 floats
    float* nj   = ws + 1048576;       // 1,048,576
    float* bias = ws + 2097152;       // 4,194,304  [B,H,I,J]
    float* q_ws = ws + 6291456;       // 262,144
    float* k_ws = ws + 6553600;       // 262,144
    float* v_ws = ws + 6815744;       // 262,144
    float* g_ws = ws + 7077888;       // 262,144
    float* o_ws = ws + 7340032;       // 262,144
    short* gwfB = (short*)(ws + 7602176);  // 2048 shorts (4 KB), 16B-aligned
    float* AB   = ws + 7603200;       // 16 floats

    k_fold<<<dim3(1), 256, 0, stream>>>(ln_p_g, ln_p_b, w_pb, w_pg, gwfB, AB);
    k_ln_nodes<<<dim3(512, 2), 256, 0, stream>>>(node_i, node_j, ln_i_g, ln_i_b,
                                                 ln_j_g, ln_j_b, ni, nj);
    k_pair_bias<<<dim3(16384), 256, 0, stream>>>(pair, pmask, gwfB, AB, bias);
    k_proj<<<dim3(128, 4), 256, 0, stream>>>(ni, nj, wq, wk, wv, wg, bg,
                                             q_ws, k_ws, v_ws, g_ws);
    k_attn<<<dim3(32, 16), 256, 0, stream>>>(q_ws, k_ws, v_ws, bias, o_ws);
    k_out<<<dim3(256), 256, 0, stream>>>(o_ws, g_ws, ni, wo, bo, nmask, out);
}

// Round 4
// 284.265 us; speedup vs baseline: 2.2929x; 1.0286x over previous
//
#include <hip/hip_runtime.h>
#include <hip/hip_bf16.h>

#define B_ 4
#define I_ 512
#define J_ 512
#define C_ 512
#define P_ 128
#define H_ 4
#define D_ 32
#define HD_ 128
#define EPS_ 1e-5f
#define INF_ 1.0e9f

typedef __attribute__((ext_vector_type(8))) short bf16x8;
typedef __attribute__((ext_vector_type(4))) float f32x4;

__device__ __forceinline__ float dot4(float4 a, float4 b) {
    return a.x * b.x + a.y * b.y + a.z * b.z + a.w * b.w;
}

// fp32 -> bf16 raw bits; plain cast lets the compiler pack pairs into
// v_cvt_pk_bf16_f32 (m240: hand-asm cvt_pk regresses, compiler handles it)
__device__ __forceinline__ short f2bf(float f) {
    return __bfloat16_as_short(__float2bfloat16(f));
}

// ---------------------------------------------------------------------------
// K1: merged prep.
//   blocks 0..1023: LayerNorm of node_embed_i (0..511) / node_embed_j
//                   (512..1023), 4 rows/block, one wave per row.
//   block 1024:     fold LN gamma into pair->head weights as MFMA B-frags
//                   (all 256 threads) + AB[16] via LDS-parallel reduce.
// grid: 1025 blocks, 256 threads
// ---------------------------------------------------------------------------
__global__ __launch_bounds__(256) void k_prep(
    const float* __restrict__ xi, const float* __restrict__ xj,
    const float* __restrict__ g_i, const float* __restrict__ b_i,
    const float* __restrict__ g_j, const float* __restrict__ b_j,
    const float* __restrict__ lng, const float* __restrict__ lnb,
    const float* __restrict__ wpb, const float* __restrict__ wpg,
    float* __restrict__ ni, float* __restrict__ nj,
    short* __restrict__ gwfB, float* __restrict__ AB)
{
    const int bx  = blockIdx.x;
    const int tid = threadIdx.x;

    if (bx < 1024) {
        const int which = bx >> 9;
        const float* x  = which ? xj  : xi;
        const float* gg = which ? g_j : g_i;
        const float* bb = which ? b_j : b_i;
        float* o        = which ? nj  : ni;

        const int row  = (bx & 511) * 4 + (tid >> 6);
        const int lane = tid & 63;

        const float* xr = x + (size_t)row * C_ + lane * 8;
        float4 v0 = *(const float4*)xr;
        float4 v1 = *(const float4*)(xr + 4);

        float s  = v0.x + v0.y + v0.z + v0.w + v1.x + v1.y + v1.z + v1.w;
        float sq = v0.x*v0.x + v0.y*v0.y + v0.z*v0.z + v0.w*v0.w
                 + v1.x*v1.x + v1.y*v1.y + v1.z*v1.z + v1.w*v1.w;
#pragma unroll
        for (int m = 1; m <= 32; m <<= 1) {
            s  += __shfl_xor(s, m);
            sq += __shfl_xor(sq, m);
        }
        const float mean = s * (1.0f / C_);
        const float var  = sq * (1.0f / C_) - mean * mean;
        const float rstd = rsqrtf(var + EPS_);

        float4 ga  = *(const float4*)(gg + lane * 8);
        float4 gb  = *(const float4*)(gg + lane * 8 + 4);
        float4 ba  = *(const float4*)(bb + lane * 8);
        float4 bb4 = *(const float4*)(bb + lane * 8 + 4);

        float4 r0, r1;
        r0.x = (v0.x - mean) * rstd * ga.x + ba.x;
        r0.y = (v0.y - mean) * rstd * ga.y + ba.y;
        r0.z = (v0.z - mean) * rstd * ga.z + ba.z;
        r0.w = (v0.w - mean) * rstd * ga.w + ba.w;
        r1.x = (v1.x - mean) * rstd * gb.x + bb4.x;
        r1.y = (v1.y - mean) * rstd * gb.y + bb4.y;
        r1.z = (v1.z - mean) * rstd * gb.z + bb4.z;
        r1.w = (v1.w - mean) * rstd * gb.w + bb4.w;

        float* orow = o + (size_t)row * C_ + lane * 8;
        *(float4*)orow       = r0;
        *(float4*)(orow + 4) = r1;
    } else {
        // ---- fold path ----
        __shared__ float sAB[P_ * 16];   // 8 KB partials
        const int s = tid >> 6, lane = tid & 63;
        const int c = lane >> 4, n = lane & 15;
#pragma unroll
        for (int e = 0; e < 8; e++) {
            const int p = s * 32 + c * 8 + e;
            const float w = (n < 4) ? wpb[p * 4 + n]
                          : (n < 8) ? wpg[p * 4 + (n - 4)] : 0.0f;
            gwfB[(s * 64 + lane) * 8 + e] = f2bf(lng[p] * w);
        }
        if (tid < P_) {
            const int p = tid;
            const float g = lng[p], b = lnb[p];
#pragma unroll
            for (int h = 0; h < 4; h++) {
                const float wb = wpb[p * 4 + h], wg = wpg[p * 4 + h];
                sAB[p * 16 + h]      = g * wb;
                sAB[p * 16 + 4 + h]  = g * wg;
                sAB[p * 16 + 8 + h]  = b * wb;
                sAB[p * 16 + 12 + h] = b * wg;
            }
        }
        __syncthreads();
        if (tid < 16) {
            float a = 0.0f;
            for (int p = 0; p < P_; p++) a += sAB[p * 16 + tid];
            AB[tid] = a;
        }
    }
}

// ---------------------------------------------------------------------------
// K2: pair path via MFMA. One wave per 16-row tile (16 consecutive j of one
// (b,i)). A = x rows (bf16-converted), B = folded weights (resident frags).
// s/sq on VALU with 2-lane-hop reduce; epilogue via C-layout
// (col=lane&15=head, row=(lane>>4)*4+reg = j offset)  [m89-verified].
// grid: (B*I*J/16/4), block: 256 (4 waves = 4 tiles)
// ---------------------------------------------------------------------------
__global__ __launch_bounds__(256, 4) void k_pair_bias(
    const float* __restrict__ pair, const int* __restrict__ pmask,
    const short* __restrict__ gwfB, const float* __restrict__ AB,
    float* __restrict__ bias)
{
    const int lane = threadIdx.x & 63;
    const int wid  = threadIdx.x >> 6;
    const int tile = blockIdx.x * 4 + wid;
    const int base = tile * 16;            // flat (b,i,j) row base
    const int r    = lane & 15;            // A row / C col index
    const int c    = lane >> 4;            // k-chunk / C row-group

    // ---- loads (all independent, issue early) ----
    const float* xp = pair + (size_t)(base + r) * P_ + c * 8;
    f32x4 xa[4], xb[4];
#pragma unroll
    for (int s = 0; s < 4; s++) {
        xa[s] = *(const f32x4*)(xp + s * 32);
        xb[s] = *(const f32x4*)(xp + s * 32 + 4);
    }
    bf16x8 bfrag[4];
#pragma unroll
    for (int s = 0; s < 4; s++)
        bfrag[s] = *(const bf16x8*)(gwfB + (s * 64 + lane) * 8);

    const float pm = (float)pmask[base + r];
    const int n4 = r & 3;
    const float Al = AB[n4], Ag = AB[4 + n4], Bl = AB[8 + n4], Bg = AB[12 + n4];

    // ---- per-kstep: convert to bf16, accumulate s/sq, MFMA ----
    f32x4 acc = {0.0f, 0.0f, 0.0f, 0.0f};
    float sum = 0.0f, sq = 0.0f;
#pragma unroll
    for (int s = 0; s < 4; s++) {
        const float e0 = xa[s].x, e1 = xa[s].y, e2 = xa[s].z, e3 = xa[s].w;
        const float e4 = xb[s].x, e5 = xb[s].y, e6 = xb[s].z, e7 = xb[s].w;
        sum += e0 + e1 + e2 + e3 + e4 + e5 + e6 + e7;
        sq = fmaf(e0, e0, sq); sq = fmaf(e1, e1, sq);
        sq = fmaf(e2, e2, sq); sq = fmaf(e3, e3, sq);
        sq = fmaf(e4, e4, sq); sq = fmaf(e5, e5, sq);
        sq = fmaf(e6, e6, sq); sq = fmaf(e7, e7, sq);
        bf16x8 afrag;
        afrag[0] = f2bf(e0); afrag[1] = f2bf(e1);
        afrag[2] = f2bf(e2); afrag[3] = f2bf(e3);
        afrag[4] = f2bf(e4); afrag[5] = f2bf(e5);
        afrag[6] = f2bf(e6); afrag[7] = f2bf(e7);
        acc = __builtin_amdgcn_mfma_f32_16x16x32_bf16(afrag, bfrag[s], acc, 0, 0, 0);
    }

    // ---- row stats: lanes {r, r+16, r+32, r+48} cover row r's 128 elems ----
    sum += __shfl_xor(sum, 16); sum += __shfl_xor(sum, 32);
    sq  += __shfl_xor(sq, 16);  sq  += __shfl_xor(sq, 32);
    const float mean = sum * (1.0f / P_);
    const float rstd = rsqrtf(sq * (1.0f / P_) - mean * mean + EPS_);
    const float mr   = mean * rstd;
    const float mb   = INF_ * (pm - 1.0f);

    // ---- epilogue ----
    const int j0 = base & (J_ - 1);
    const int i  = (base >> 9) & (I_ - 1);
    const int b  = base >> 18;
    float* obase = bias + (((size_t)(b * H_ + n4) * I_ + i) << 9) + j0;

#pragma unroll
    for (int reg = 0; reg < 4; reg++) {
        const int rr = c * 4 + reg;               // C row = local j
        const float rstd_r = __shfl(rstd, rr);    // lane rr holds row rr stats
        const float mr_r   = __shfl(mr, rr);
        const float mb_r   = __shfl(mb, rr);
        const float Sg     = __shfl(acc[reg], lane + 4);  // gate logit lives at col+4
        if (r < 4) {
            const float left = fmaf(rstd_r, acc[reg], fmaf(-mr_r, Al, Bl));
            const float glog = fmaf(rstd_r, Sg,       fmaf(-mr_r, Ag, Bg));
            const float val  = left * (1.0f / (1.0f + __expf(-glog))) + mb_r;
            obase[rr] = val;
        }
    }
}

// ---------------------------------------------------------------------------
// K3: projections q,k,v,g. blockIdx.y selects the matrix. 16-row A tile in
// LDS (broadcast reads); weights streamed from L2.
// grid: (B*I/16, 4), block: 256
// ---------------------------------------------------------------------------
__global__ __launch_bounds__(256) void k_proj(
    const float* __restrict__ ni, const float* __restrict__ nj,
    const float* __restrict__ wq, const float* __restrict__ wk,
    const float* __restrict__ wv, const float* __restrict__ wg,
    const float* __restrict__ bg,
    float* __restrict__ q_ws, float* __restrict__ k_ws,
    float* __restrict__ v_ws, float* __restrict__ g_ws)
{
    __shared__ float s_src[16 * 512];
    const int y    = blockIdx.y;
    const int tid  = threadIdx.x;
    const int base = blockIdx.x * 16;   // row in [0, B*I)

    const float* src = (y == 0 || y == 3) ? ni : nj;
    const float* W   = (y == 0) ? wq : (y == 1) ? wk : (y == 2) ? wv : wg;

    const float* sg = src + (size_t)base * C_;
#pragma unroll
    for (int rep = 0; rep < 8; rep++) {
        const int flat = rep * 1024 + tid * 4;
        *(float4*)&s_src[flat] = *(const float4*)(sg + flat);
    }
    __syncthreads();

    const int col = tid & 127;
    const int r0  = (tid >> 7) * 8;
    float acc[8] = {0, 0, 0, 0, 0, 0, 0, 0};

#pragma unroll 4
    for (int c = 0; c < C_; c++) {
        const float w = W[c * HD_ + col];
#pragma unroll
        for (int r = 0; r < 8; r++) acc[r] += s_src[(r0 + r) * 512 + c] * w;
    }

    if (y == 3) {
        const float bgc = bg[col];
#pragma unroll
        for (int r = 0; r < 8; r++) {
            const float gv = 1.0f / (1.0f + __expf(-(acc[r] + bgc)));
            g_ws[(size_t)(base + r0 + r) * HD_ + col] = gv;
        }
    } else {
        const int b  = base >> 9;
        const int i0 = base & 511;
        const int h  = col >> 5, d = col & 31;
        const float scale = (y == 0) ? 0.17677669529663689f : 1.0f;  // 1/sqrt(32)
        float* dst = (y == 0) ? q_ws : (y == 1) ? k_ws : v_ws;
#pragma unroll
        for (int r = 0; r < 8; r++)
            dst[((size_t)(b * H_ + h) * 512 + i0 + r0 + r) * D_ + d] = acc[r] * scale;
    }
}

// ---------------------------------------------------------------------------
// K4: attention for one (b,h) and a 16-row i tile.
// grid: (I/16, B*H), block: 256
// ---------------------------------------------------------------------------
__global__ __launch_bounds__(256) void k_attn(
    const float* __restrict__ q_ws, const float* __restrict__ k_ws,
    const float* __restrict__ v_ws, const float* __restrict__ bias,
    float* __restrict__ o_ws)
{
    __shared__ float s_a[16 * 520];
    const int tid = threadIdx.x;
    const int bh  = blockIdx.y;          // b*H + h
    const int b   = bh >> 2, h = bh & 3;
    const int i0  = blockIdx.x * 16;
    const int i   = tid >> 4;
    const int l16 = tid & 15;

    const float* qrow = q_ws + ((size_t)bh * I_ + i0 + i) * D_;
    const float4 q0 = *(const float4*)(qrow);
    const float4 q1 = *(const float4*)(qrow + 4);
    const float4 q2 = *(const float4*)(qrow + 8);
    const float4 q3 = *(const float4*)(qrow + 12);
    const float4 q4 = *(const float4*)(qrow + 16);
    const float4 q5 = *(const float4*)(qrow + 20);
    const float4 q6 = *(const float4*)(qrow + 24);
    const float4 q7 = *(const float4*)(qrow + 28);

    float acc[32];
    const float* brow = bias + ((size_t)bh * I_ + i0 + i) * J_;
#pragma unroll
    for (int e = 0; e < 32; e++) acc[e] = brow[l16 + 16 * e];

    const float* kbase = k_ws + (size_t)bh * J_ * D_;
#pragma unroll
    for (int e = 0; e < 32; e++) {
        const float* kp = kbase + (l16 + 16 * e) * D_;
        const float4 k0 = *(const float4*)(kp);
        const float4 k1 = *(const float4*)(kp + 4);
        const float4 k2 = *(const float4*)(kp + 8);
        const float4 k3 = *(const float4*)(kp + 12);
        const float4 k4 = *(const float4*)(kp + 16);
        const float4 k5 = *(const float4*)(kp + 20);
        const float4 k6 = *(const float4*)(kp + 24);
        const float4 k7 = *(const float4*)(kp + 28);
        acc[e] += dot4(q0, k0) + dot4(q1, k1) + dot4(q2, k2) + dot4(q3, k3)
                + dot4(q4, k4) + dot4(q5, k5) + dot4(q6, k6) + dot4(q7, k7);
    }

    float mx = acc[0];
#pragma unroll
    for (int e = 1; e < 32; e++) mx = fmaxf(mx, acc[e]);
#pragma unroll
    for (int m = 1; m < 16; m <<= 1) mx = fmaxf(mx, __shfl_xor(mx, m));
    float sum = 0.0f;
#pragma unroll
    for (int e = 0; e < 32; e++) { acc[e] = __expf(acc[e] - mx); sum += acc[e]; }
#pragma unroll
    for (int m = 1; m < 16; m <<= 1) sum += __shfl_xor(sum, m);
#pragma unroll
    for (int e = 0; e < 32; e++) s_a[i * 520 + l16 + 16 * e] = acc[e];
    const float scale = 1.0f / sum;
    __syncthreads();

    const int dg = l16;
    const float* vbase = v_ws + (size_t)bh * J_ * D_ + 2 * dg;
    float o0 = 0.0f, o1 = 0.0f;
#pragma unroll 8
    for (int jj = 0; jj < J_; jj++) {
        const float a = s_a[i * 520 + jj];
        const float2 vv = *(const float2*)(vbase + (size_t)jj * D_);
        o0 += a * vv.x;
        o1 += a * vv.y;
    }
    float* op = o_ws + ((size_t)(b * I_ + i0 + i)) * HD_ + h * D_ + 2 * dg;
    op[0] = o0 * scale;
    op[1] = o1 * scale;
}

// ---------------------------------------------------------------------------
// K5: out = ni + ((o*g) @ wo + bo) * node_mask.
// grid: (B*I/8), block: 256
// ---------------------------------------------------------------------------
__global__ __launch_bounds__(256) void k_out(
    const float* __restrict__ o_ws, const float* __restrict__ g_ws,
    const float* __restrict__ ni, const float* __restrict__ wo,
    const float* __restrict__ bo, const int* __restrict__ nmask,
    float* __restrict__ out)
{
    __shared__ float s_og[8 * 128];
    const int tid  = threadIdx.x;
    const int base = blockIdx.x * 8;     // row in [0, B*I)

#pragma unroll
    for (int rep = 0; rep < 4; rep++) {
        const int flat = rep * 256 + tid;
        s_og[flat] = o_ws[(size_t)base * HD_ + flat] * g_ws[(size_t)base * HD_ + flat];
    }
    __syncthreads();

    const int c0 = tid * 2;
    float a0[8] = {0, 0, 0, 0, 0, 0, 0, 0};
    float a1[8] = {0, 0, 0, 0, 0, 0, 0, 0};

#pragma unroll 4
    for (int hd = 0; hd < HD_; hd++) {
        const float2 w = *(const float2*)(wo + hd * C_ + c0);
#pragma unroll
        for (int r = 0; r < 8; r++) {
            const float v = s_og[r * 128 + hd];
            a0[r] += v * w.x;
            a1[r] += v * w.y;
        }
    }

    const float b0v = bo[c0], b1v = bo[c0 + 1];
#pragma unroll
    for (int r = 0; r < 8; r++) {
        const int row = base + r;
        const float mk = (float)nmask[row];
        const size_t off = (size_t)row * C_ + c0;
        out[off]     = ni[off]     + (a0[r] + b0v) * mk;
        out[off + 1] = ni[off + 1] + (a1[r] + b1v) * mk;
    }
}

// ---------------------------------------------------------------------------
extern "C" void kernel_launch(void* const* d_in, const int* in_sizes, int n_in,
                              void* d_out, int out_size, void* d_ws, size_t ws_size,
                              hipStream_t stream)
{
    const float* node_i = (const float*)d_in[0];
    const float* node_j = (const float*)d_in[1];
    const float* pair   = (const float*)d_in[2];
    const int*   pmask  = (const int*)d_in[3];
    const int*   nmask  = (const int*)d_in[4];
    const float* ln_i_g = (const float*)d_in[5];
    const float* ln_i_b = (const float*)d_in[6];
    const float* ln_j_g = (const float*)d_in[7];
    const float* ln_j_b = (const float*)d_in[8];
    const float* ln_p_g = (const float*)d_in[9];
    const float* ln_p_b = (const float*)d_in[10];
    const float* w_pb   = (const float*)d_in[11];
    const float* w_pg   = (const float*)d_in[12];
    const float* wq     = (const float*)d_in[13];
    const float* wk     = (const float*)d_in[14];
    const float* wv     = (const float*)d_in[15];
    const float* wg     = (const float*)d_in[16];
    const float* bg     = (const float*)d_in[17];
    const float* wo     = (const float*)d_in[18];
    const float* bo     = (const float*)d_in[19];

    float* out = (float*)d_out;
    float* ws  = (float*)d_ws;

    float* ni   = ws;                 // 1,048,576 floats
    float* nj   = ws + 1048576;       // 1,048,576
    float* bias = ws + 2097152;       // 4,194,304  [B,H,I,J]
    float* q_ws = ws + 6291456;       // 262,144
    float* k_ws = ws + 6553600;       // 262,144
    float* v_ws = ws + 6815744;       // 262,144
    float* g_ws = ws + 7077888;       // 262,144
    float* o_ws = ws + 7340032;       // 262,144
    short* gwfB = (short*)(ws + 7602176);  // 2048 shorts (4 KB), 16B-aligned
    float* AB   = ws + 7603200;       // 16 floats

    k_prep<<<dim3(1025), 256, 0, stream>>>(node_i, node_j, ln_i_g, ln_i_b,
                                           ln_j_g, ln_j_b, ln_p_g, ln_p_b,
                                           w_pb, w_pg, ni, nj, gwfB, AB);
    k_pair_bias<<<dim3(16384), 256, 0, stream>>>(pair, pmask, gwfB, AB, bias);
    k_proj<<<dim3(128, 4), 256, 0, stream>>>(ni, nj, wq, wk, wv, wg, bg,
                                             q_ws, k_ws, v_ws, g_ws);
    k_attn<<<dim3(32, 16), 256, 0, stream>>>(q_ws, k_ws, v_ws, bias, o_ws);
    k_out<<<dim3(256), 256, 0, stream>>>(o_ws, g_ws, ni, wo, bo, nmask, out);
}

// Round 5
// 192.049 us; speedup vs baseline: 3.3938x; 1.4802x over previous
//
#include <hip/hip_runtime.h>
#include <hip/hip_bf16.h>

#define B_ 4
#define I_ 512
#define J_ 512
#define C_ 512
#define P_ 128
#define H_ 4
#define D_ 32
#define HD_ 128
#define EPS_ 1e-5f
#define INF_ 1.0e9f
#define QSCALE_ 0.17677669529663689f

typedef __attribute__((ext_vector_type(8))) short bf16x8;
typedef __attribute__((ext_vector_type(4))) short s16x4;
typedef __attribute__((ext_vector_type(4))) float f32x4;

// fp32 -> bf16 raw bits; plain cast lets the compiler pack v_cvt_pk_bf16_f32
__device__ __forceinline__ short f2bf(float f) {
    return __bfloat16_as_short(__float2bfloat16(f));
}

// ---------------------------------------------------------------------------
// K1: merged prep.
//   blocks 0..1023:   LayerNorm of node_i / node_j (4 rows/block, wave/row)
//   block 1024:       fold LN gamma into pair->head weights (MFMA B-frags)
//                     + AB[16] via LDS-parallel reduce
//   blocks 1025..1056: transpose {wq,wk,wv,wg} -> wT[m][col][c] bf16
//                     (q-scale folded into wT[0])
// grid: 1057 blocks, 256 threads
// ---------------------------------------------------------------------------
__global__ __launch_bounds__(256) void k_prep(
    const float* __restrict__ xi, const float* __restrict__ xj,
    const float* __restrict__ g_i, const float* __restrict__ b_i,
    const float* __restrict__ g_j, const float* __restrict__ b_j,
    const float* __restrict__ lng, const float* __restrict__ lnb,
    const float* __restrict__ wpb, const float* __restrict__ wpg,
    const float* __restrict__ wq, const float* __restrict__ wk,
    const float* __restrict__ wv, const float* __restrict__ wg,
    float* __restrict__ ni, float* __restrict__ nj,
    short* __restrict__ gwfB, float* __restrict__ AB,
    short* __restrict__ wT)
{
    const int bx  = blockIdx.x;
    const int tid = threadIdx.x;

    if (bx < 1024) {
        const int which = bx >> 9;
        const float* x  = which ? xj  : xi;
        const float* gg = which ? g_j : g_i;
        const float* bb = which ? b_j : b_i;
        float* o        = which ? nj  : ni;

        const int row  = (bx & 511) * 4 + (tid >> 6);
        const int lane = tid & 63;

        const float* xr = x + (size_t)row * C_ + lane * 8;
        float4 v0 = *(const float4*)xr;
        float4 v1 = *(const float4*)(xr + 4);

        float s  = v0.x + v0.y + v0.z + v0.w + v1.x + v1.y + v1.z + v1.w;
        float sq = v0.x*v0.x + v0.y*v0.y + v0.z*v0.z + v0.w*v0.w
                 + v1.x*v1.x + v1.y*v1.y + v1.z*v1.z + v1.w*v1.w;
#pragma unroll
        for (int m = 1; m <= 32; m <<= 1) {
            s  += __shfl_xor(s, m);
            sq += __shfl_xor(sq, m);
        }
        const float mean = s * (1.0f / C_);
        const float var  = sq * (1.0f / C_) - mean * mean;
        const float rstd = rsqrtf(var + EPS_);

        float4 ga  = *(const float4*)(gg + lane * 8);
        float4 gb  = *(const float4*)(gg + lane * 8 + 4);
        float4 ba  = *(const float4*)(bb + lane * 8);
        float4 bb4 = *(const float4*)(bb + lane * 8 + 4);

        float4 r0, r1;
        r0.x = (v0.x - mean) * rstd * ga.x + ba.x;
        r0.y = (v0.y - mean) * rstd * ga.y + ba.y;
        r0.z = (v0.z - mean) * rstd * ga.z + ba.z;
        r0.w = (v0.w - mean) * rstd * ga.w + ba.w;
        r1.x = (v1.x - mean) * rstd * gb.x + bb4.x;
        r1.y = (v1.y - mean) * rstd * gb.y + bb4.y;
        r1.z = (v1.z - mean) * rstd * gb.z + bb4.z;
        r1.w = (v1.w - mean) * rstd * gb.w + bb4.w;

        float* orow = o + (size_t)row * C_ + lane * 8;
        *(float4*)orow       = r0;
        *(float4*)(orow + 4) = r1;
    } else if (bx == 1024) {
        // ---- fold path ----
        __shared__ float sAB[P_ * 16];
        const int s = tid >> 6, lane = tid & 63;
        const int c = lane >> 4, n = lane & 15;
#pragma unroll
        for (int e = 0; e < 8; e++) {
            const int p = s * 32 + c * 8 + e;
            const float w = (n < 4) ? wpb[p * 4 + n]
                          : (n < 8) ? wpg[p * 4 + (n - 4)] : 0.0f;
            gwfB[(s * 64 + lane) * 8 + e] = f2bf(lng[p] * w);
        }
        if (tid < P_) {
            const int p = tid;
            const float g = lng[p], b = lnb[p];
#pragma unroll
            for (int h = 0; h < 4; h++) {
                const float wb = wpb[p * 4 + h], wgv = wpg[p * 4 + h];
                sAB[p * 16 + h]      = g * wb;
                sAB[p * 16 + 4 + h]  = g * wgv;
                sAB[p * 16 + 8 + h]  = b * wb;
                sAB[p * 16 + 12 + h] = b * wgv;
            }
        }
        __syncthreads();
        if (tid < 16) {
            float a = 0.0f;
            for (int p = 0; p < P_; p++) a += sAB[p * 16 + tid];
            AB[tid] = a;
        }
    } else {
        // ---- weight transpose: wT[m][col][c] (bf16) ----
        const int bx2 = bx - 1025;          // 0..31
        const int m  = bx2 >> 3, cg = bx2 & 7;
        const float* W = (m == 0) ? wq : (m == 1) ? wk : (m == 2) ? wv : wg;
        const float scale = (m == 0) ? QSCALE_ : 1.0f;
        const int col = cg * 16 + (tid & 15);
        const int c0  = (tid >> 4) * 32;
        short* dst = wT + m * 65536 + col * 512 + c0;
#pragma unroll
        for (int c4 = 0; c4 < 8; c4++) {
            s16x4 pk;
#pragma unroll
            for (int u = 0; u < 4; u++)
                pk[u] = f2bf(W[(size_t)(c0 + c4 * 4 + u) * HD_ + col] * scale);
            *(s16x4*)(dst + c4 * 4) = pk;
        }
    }
}

// ---------------------------------------------------------------------------
// K2: pair path via MFMA (unchanged from round 3/4 - verified).
// grid: (B*I*J/64), block: 256 (4 waves = 4 tiles of 16 rows)
// ---------------------------------------------------------------------------
__global__ __launch_bounds__(256, 4) void k_pair_bias(
    const float* __restrict__ pair, const int* __restrict__ pmask,
    const short* __restrict__ gwfB, const float* __restrict__ AB,
    float* __restrict__ bias)
{
    const int lane = threadIdx.x & 63;
    const int wid  = threadIdx.x >> 6;
    const int tile = blockIdx.x * 4 + wid;
    const int base = tile * 16;
    const int r    = lane & 15;
    const int c    = lane >> 4;

    const float* xp = pair + (size_t)(base + r) * P_ + c * 8;
    f32x4 xa[4], xb[4];
#pragma unroll
    for (int s = 0; s < 4; s++) {
        xa[s] = *(const f32x4*)(xp + s * 32);
        xb[s] = *(const f32x4*)(xp + s * 32 + 4);
    }
    bf16x8 bfrag[4];
#pragma unroll
    for (int s = 0; s < 4; s++)
        bfrag[s] = *(const bf16x8*)(gwfB + (s * 64 + lane) * 8);

    const float pm = (float)pmask[base + r];
    const int n4 = r & 3;
    const float Al = AB[n4], Ag = AB[4 + n4], Bl = AB[8 + n4], Bg = AB[12 + n4];

    f32x4 acc = {0.0f, 0.0f, 0.0f, 0.0f};
    float sum = 0.0f, sq = 0.0f;
#pragma unroll
    for (int s = 0; s < 4; s++) {
        const float e0 = xa[s].x, e1 = xa[s].y, e2 = xa[s].z, e3 = xa[s].w;
        const float e4 = xb[s].x, e5 = xb[s].y, e6 = xb[s].z, e7 = xb[s].w;
        sum += e0 + e1 + e2 + e3 + e4 + e5 + e6 + e7;
        sq = fmaf(e0, e0, sq); sq = fmaf(e1, e1, sq);
        sq = fmaf(e2, e2, sq); sq = fmaf(e3, e3, sq);
        sq = fmaf(e4, e4, sq); sq = fmaf(e5, e5, sq);
        sq = fmaf(e6, e6, sq); sq = fmaf(e7, e7, sq);
        bf16x8 afrag;
        afrag[0] = f2bf(e0); afrag[1] = f2bf(e1);
        afrag[2] = f2bf(e2); afrag[3] = f2bf(e3);
        afrag[4] = f2bf(e4); afrag[5] = f2bf(e5);
        afrag[6] = f2bf(e6); afrag[7] = f2bf(e7);
        acc = __builtin_amdgcn_mfma_f32_16x16x32_bf16(afrag, bfrag[s], acc, 0, 0, 0);
    }

    sum += __shfl_xor(sum, 16); sum += __shfl_xor(sum, 32);
    sq  += __shfl_xor(sq, 16);  sq  += __shfl_xor(sq, 32);
    const float mean = sum * (1.0f / P_);
    const float rstd = rsqrtf(sq * (1.0f / P_) - mean * mean + EPS_);
    const float mr   = mean * rstd;
    const float mb   = INF_ * (pm - 1.0f);

    const int j0 = base & (J_ - 1);
    const int i  = (base >> 9) & (I_ - 1);
    const int b  = base >> 18;
    float* obase = bias + (((size_t)(b * H_ + n4) * I_ + i) << 9) + j0;

#pragma unroll
    for (int reg = 0; reg < 4; reg++) {
        const int rr = c * 4 + reg;
        const float rstd_r = __shfl(rstd, rr);
        const float mr_r   = __shfl(mr, rr);
        const float mb_r   = __shfl(mb, rr);
        const float Sg     = __shfl(acc[reg], lane + 4);
        if (r < 4) {
            const float left = fmaf(rstd_r, acc[reg], fmaf(-mr_r, Al, Bl));
            const float glog = fmaf(rstd_r, Sg,       fmaf(-mr_r, Ag, Bg));
            const float val  = left * (1.0f / (1.0f + __expf(-glog))) + mb_r;
            obase[rr] = val;
        }
    }
}

// ---------------------------------------------------------------------------
// K3: projections via bf16 MFMA, direct-from-L2 fragments (no LDS).
// Wave = 16 rows x 128 cols x K=512 -> 128 MFMAs. Outputs: q_bf/k_bf
// ([bh][row][d] bf16, q pre-scaled via wT), vT_bf ([bh][d][j] bf16),
// g_ws (f32, sigmoid applied).
// grid: (B*I/32, 4), block: 128 (2 waves)
// ---------------------------------------------------------------------------
__global__ __launch_bounds__(128) void k_proj(
    const float* __restrict__ ni, const float* __restrict__ nj,
    const short* __restrict__ wT, const float* __restrict__ bg,
    short* __restrict__ q_bf, short* __restrict__ k_bf,
    short* __restrict__ vT_bf, float* __restrict__ g_ws)
{
    const int m    = blockIdx.y;
    const int w    = threadIdx.x >> 6;
    const int lane = threadIdx.x & 63;
    const int r    = lane & 15;
    const int cgrp = lane >> 4;
    const int i0   = blockIdx.x * 32 + w * 16;      // row in [0, B*I)
    const float* src = (m == 0 || m == 3) ? ni : nj;
    const short* wbase = wT + m * 65536 + cgrp * 8;

    f32x4 acc[8];
#pragma unroll
    for (int nt = 0; nt < 8; nt++) acc[nt] = (f32x4){0.0f, 0.0f, 0.0f, 0.0f};

    const float* arow = src + (size_t)(i0 + r) * C_ + cgrp * 8;
#pragma unroll 4
    for (int kk = 0; kk < 16; kk++) {
        const f32x4 a0 = *(const f32x4*)(arow + kk * 32);
        const f32x4 a1 = *(const f32x4*)(arow + kk * 32 + 4);
        bf16x8 af;
        af[0] = f2bf(a0.x); af[1] = f2bf(a0.y); af[2] = f2bf(a0.z); af[3] = f2bf(a0.w);
        af[4] = f2bf(a1.x); af[5] = f2bf(a1.y); af[6] = f2bf(a1.z); af[7] = f2bf(a1.w);
#pragma unroll
        for (int nt = 0; nt < 8; nt++) {
            const bf16x8 bf = *(const bf16x8*)(wbase + (nt * 16 + r) * 512 + kk * 32);
            acc[nt] = __builtin_amdgcn_mfma_f32_16x16x32_bf16(af, bf, acc[nt], 0, 0, 0);
        }
    }

    const int b  = i0 >> 9;
    const int il = i0 & 511;
#pragma unroll
    for (int nt = 0; nt < 8; nt++) {
        const int col = nt * 16 + r;
        if (m == 3) {
            const float bgc = bg[col];
#pragma unroll
            for (int reg = 0; reg < 4; reg++) {
                const int row = i0 + cgrp * 4 + reg;
                g_ws[(size_t)row * HD_ + col] =
                    1.0f / (1.0f + __expf(-(acc[nt][reg] + bgc)));
            }
        } else if (m == 2) {
            const int h = col >> 5, d = col & 31;
            const int j = il + cgrp * 4;
            s16x4 pk;
            pk[0] = f2bf(acc[nt][0]); pk[1] = f2bf(acc[nt][1]);
            pk[2] = f2bf(acc[nt][2]); pk[3] = f2bf(acc[nt][3]);
            *(s16x4*)(vT_bf + ((size_t)(b * H_ + h) * D_ + d) * J_ + j) = pk;
        } else {
            short* dst = (m == 0) ? q_bf : k_bf;
            const int h = col >> 5, d = col & 31;
#pragma unroll
            for (int reg = 0; reg < 4; reg++) {
                const int i = il + cgrp * 4 + reg;
                dst[((size_t)(b * H_ + h) * 512 + i) * D_ + d] = f2bf(acc[nt][reg]);
            }
        }
    }
}

// ---------------------------------------------------------------------------
// K4: attention via MFMA. Block = (bh, 16-i tile), 4 waves.
// QK^T: wave w covers j in [128w, 128w+128) as 8 16x16 tiles, bias as C-init.
// Softmax: per-16-lane-group reduce + cross-wave LDS partials.
// P -> bf16 LDS (pitch 520). PV: wave = (d-tile = w&1, j-half = w>>1),
// partials summed in LDS, normalized in epilogue.
// grid: (I/16, B*H), block: 256
// ---------------------------------------------------------------------------
__global__ __launch_bounds__(256) void k_attn(
    const short* __restrict__ q_bf, const short* __restrict__ k_bf,
    const short* __restrict__ vT_bf, const float* __restrict__ bias,
    float* __restrict__ o_ws)
{
    __shared__ short s_p[16 * 520];       // P bf16, pitch 520
    __shared__ float s_red[2 * 4 * 16];   // [max|sum][wave][row]
    __shared__ float s_o[2 * 16 * 34];    // [j-half][row][d] padded

    const int tid  = threadIdx.x;
    const int w    = tid >> 6;
    const int lane = tid & 63;
    const int r    = lane & 15;
    const int c    = lane >> 4;
    const int bh   = blockIdx.y;
    const int i0   = blockIdx.x * 16;

    // ---- QK^T with bias C-init ----
    const bf16x8 qf = *(const bf16x8*)(q_bf + ((size_t)bh * I_ + i0 + r) * D_ + c * 8);
    f32x4 acc[8];
#pragma unroll
    for (int t = 0; t < 8; t++) {
        const int jt = w * 8 + t;
        const float* bp = bias + ((size_t)bh * I_ + i0 + c * 4) * J_ + jt * 16 + r;
        f32x4 ci;
        ci[0] = bp[0]; ci[1] = bp[J_]; ci[2] = bp[2 * J_]; ci[3] = bp[3 * J_];
        const bf16x8 kf = *(const bf16x8*)(k_bf + ((size_t)bh * J_ + jt * 16 + r) * D_ + c * 8);
        acc[t] = __builtin_amdgcn_mfma_f32_16x16x32_bf16(qf, kf, ci, 0, 0, 0);
    }

    // ---- row max (this wave's j-range) ----
    float mx[4];
#pragma unroll
    for (int reg = 0; reg < 4; reg++) {
        float m0 = acc[0][reg];
#pragma unroll
        for (int t = 1; t < 8; t++) m0 = fmaxf(m0, acc[t][reg]);
        mx[reg] = m0;
    }
#pragma unroll
    for (int mm = 1; mm < 16; mm <<= 1) {
#pragma unroll
        for (int reg = 0; reg < 4; reg++)
            mx[reg] = fmaxf(mx[reg], __shfl_xor(mx[reg], mm));
    }
    if (r < 4) {
        const float v = (r == 0) ? mx[0] : (r == 1) ? mx[1] : (r == 2) ? mx[2] : mx[3];
        s_red[w * 16 + c * 4 + r] = v;
    }
    __syncthreads();

    float M[4];
#pragma unroll
    for (int reg = 0; reg < 4; reg++) {
        const int row = c * 4 + reg;
        M[reg] = fmaxf(fmaxf(s_red[row], s_red[16 + row]),
                       fmaxf(s_red[32 + row], s_red[48 + row]));
    }

    // ---- p = exp(logit - M), store bf16 to LDS, accumulate sums ----
    float sm[4] = {0.0f, 0.0f, 0.0f, 0.0f};
#pragma unroll
    for (int t = 0; t < 8; t++) {
        const int j = (w * 8 + t) * 16 + r;
#pragma unroll
        for (int reg = 0; reg < 4; reg++) {
            const float p = __expf(acc[t][reg] - M[reg]);
            sm[reg] += p;
            s_p[(c * 4 + reg) * 520 + j] = f2bf(p);
        }
    }
#pragma unroll
    for (int mm = 1; mm < 16; mm <<= 1) {
#pragma unroll
        for (int reg = 0; reg < 4; reg++)
            sm[reg] += __shfl_xor(sm[reg], mm);
    }
    if (r < 4) {
        const float v = (r == 0) ? sm[0] : (r == 1) ? sm[1] : (r == 2) ? sm[2] : sm[3];
        s_red[64 + w * 16 + c * 4 + r] = v;
    }
    __syncthreads();

    // ---- PV: wave = (d-tile, j-half) ----
    const int nt = w & 1, jh = w >> 1;
    f32x4 oacc = {0.0f, 0.0f, 0.0f, 0.0f};
    const short* vrow = vT_bf + ((size_t)bh * D_ + nt * 16 + r) * J_ + c * 8;
#pragma unroll
    for (int kk8 = 0; kk8 < 8; kk8++) {
        const int kk = jh * 8 + kk8;
        const bf16x8 pf = *(const bf16x8*)(s_p + r * 520 + kk * 32 + c * 8);
        const bf16x8 vf = *(const bf16x8*)(vrow + kk * 32);
        oacc = __builtin_amdgcn_mfma_f32_16x16x32_bf16(pf, vf, oacc, 0, 0, 0);
    }
#pragma unroll
    for (int reg = 0; reg < 4; reg++)
        s_o[jh * 544 + (c * 4 + reg) * 34 + nt * 16 + r] = oacc[reg];
    __syncthreads();

    // ---- combine halves, normalize, write ----
    const int il = tid >> 4, dd = (tid & 15) * 2;
    const float den = s_red[64 + il] + s_red[64 + 16 + il]
                    + s_red[64 + 32 + il] + s_red[64 + 48 + il];
    const float rs = 1.0f / den;
    const float v0 = (s_o[il * 34 + dd]     + s_o[544 + il * 34 + dd])     * rs;
    const float v1 = (s_o[il * 34 + dd + 1] + s_o[544 + il * 34 + dd + 1]) * rs;
    const int b = bh >> 2, h = bh & 3;
    float* op = o_ws + ((size_t)(b * I_ + i0 + il)) * HD_ + h * D_ + dd;
    op[0] = v0; op[1] = v1;
}

// ---------------------------------------------------------------------------
// K5: out = ni + ((o*g) @ wo + bo) * node_mask.
// grid: (B*I/8), block: 256
// ---------------------------------------------------------------------------
__global__ __launch_bounds__(256) void k_out(
    const float* __restrict__ o_ws, const float* __restrict__ g_ws,
    const float* __restrict__ ni, const float* __restrict__ wo,
    const float* __restrict__ bo, const int* __restrict__ nmask,
    float* __restrict__ out)
{
    __shared__ float s_og[8 * 128];
    const int tid  = threadIdx.x;
    const int base = blockIdx.x * 8;

#pragma unroll
    for (int rep = 0; rep < 4; rep++) {
        const int flat = rep * 256 + tid;
        s_og[flat] = o_ws[(size_t)base * HD_ + flat] * g_ws[(size_t)base * HD_ + flat];
    }
    __syncthreads();

    const int c0 = tid * 2;
    float a0[8] = {0, 0, 0, 0, 0, 0, 0, 0};
    float a1[8] = {0, 0, 0, 0, 0, 0, 0, 0};

#pragma unroll 4
    for (int hd = 0; hd < HD_; hd++) {
        const float2 wv = *(const float2*)(wo + hd * C_ + c0);
#pragma unroll
        for (int r = 0; r < 8; r++) {
            const float v = s_og[r * 128 + hd];
            a0[r] += v * wv.x;
            a1[r] += v * wv.y;
        }
    }

    const float b0v = bo[c0], b1v = bo[c0 + 1];
#pragma unroll
    for (int r = 0; r < 8; r++) {
        const int row = base + r;
        const float mk = (float)nmask[row];
        const size_t off = (size_t)row * C_ + c0;
        out[off]     = ni[off]     + (a0[r] + b0v) * mk;
        out[off + 1] = ni[off + 1] + (a1[r] + b1v) * mk;
    }
}

// ---------------------------------------------------------------------------
extern "C" void kernel_launch(void* const* d_in, const int* in_sizes, int n_in,
                              void* d_out, int out_size, void* d_ws, size_t ws_size,
                              hipStream_t stream)
{
    const float* node_i = (const float*)d_in[0];
    const float* node_j = (const float*)d_in[1];
    const float* pair   = (const float*)d_in[2];
    const int*   pmask  = (const int*)d_in[3];
    const int*   nmask  = (const int*)d_in[4];
    const float* ln_i_g = (const float*)d_in[5];
    const float* ln_i_b = (const float*)d_in[6];
    const float* ln_j_g = (const float*)d_in[7];
    const float* ln_j_b = (const float*)d_in[8];
    const float* ln_p_g = (const float*)d_in[9];
    const float* ln_p_b = (const float*)d_in[10];
    const float* w_pb   = (const float*)d_in[11];
    const float* w_pg   = (const float*)d_in[12];
    const float* wq     = (const float*)d_in[13];
    const float* wk     = (const float*)d_in[14];
    const float* wv     = (const float*)d_in[15];
    const float* wg     = (const float*)d_in[16];
    const float* bg     = (const float*)d_in[17];
    const float* wo     = (const float*)d_in[18];
    const float* bo     = (const float*)d_in[19];

    float* out = (float*)d_out;
    float* ws  = (float*)d_ws;

    float* ni    = ws;                        // 1,048,576 floats
    float* nj    = ws + 1048576;              // 1,048,576
    float* bias  = ws + 2097152;              // 4,194,304  [B,H,I,J]
    float* g_ws  = ws + 6291456;              // 262,144    [B*I][HD]
    float* o_ws  = ws + 6553600;              // 262,144    [B*I][HD]
    short* q_bf  = (short*)(ws + 6815744);    // 262,144 shorts [BH][I][D]
    short* k_bf  = (short*)(ws + 6946816);    // 262,144 shorts [BH][J][D]
    short* vT_bf = (short*)(ws + 7077888);    // 262,144 shorts [BH][D][J]
    short* wT    = (short*)(ws + 7208960);    // 262,144 shorts [4][128][512]
    short* gwfB  = (short*)(ws + 7340032);    // 2,048 shorts
    float* AB    = ws + 7341056;              // 16 floats

    k_prep<<<dim3(1057), 256, 0, stream>>>(node_i, node_j, ln_i_g, ln_i_b,
                                           ln_j_g, ln_j_b, ln_p_g, ln_p_b,
                                           w_pb, w_pg, wq, wk, wv, wg,
                                           ni, nj, gwfB, AB, wT);
    k_pair_bias<<<dim3(16384), 256, 0, stream>>>(pair, pmask, gwfB, AB, bias);
    k_proj<<<dim3(64, 4), 128, 0, stream>>>(ni, nj, wT, bg,
                                            q_bf, k_bf, vT_bf, g_ws);
    k_attn<<<dim3(32, 16), 256, 0, stream>>>(q_bf, k_bf, vT_bf, bias, o_ws);
    k_out<<<dim3(256), 256, 0, stream>>>(o_ws, g_ws, ni, wo, bo, nmask, out);
}

// Round 6
// 171.567 us; speedup vs baseline: 3.7990x; 1.1194x over previous
//
#include <hip/hip_runtime.h>
#include <hip/hip_bf16.h>

#define B_ 4
#define I_ 512
#define J_ 512
#define C_ 512
#define P_ 128
#define H_ 4
#define D_ 32
#define HD_ 128
#define EPS_ 1e-5f
#define INF_ 1.0e9f
#define QSCALE_ 0.17677669529663689f

#define PB_BLOCKS 2048            // pair: persistent blocks (4 waves each)
#define PB_WAVES (PB_BLOCKS * 4)  // 8192 waves
#define PB_TILES 65536            // B*I*J/16
#define PB_ITERS (PB_TILES / PB_WAVES)  // 8 tiles per wave

typedef __attribute__((ext_vector_type(8))) short bf16x8;
typedef __attribute__((ext_vector_type(4))) short s16x4;
typedef __attribute__((ext_vector_type(4))) float f32x4;

// fp32 -> bf16 raw bits; plain cast lets the compiler pack v_cvt_pk_bf16_f32
__device__ __forceinline__ short f2bf(float f) {
    return __bfloat16_as_short(__float2bfloat16(f));
}

// ---------------------------------------------------------------------------
// K1: merged prep.
//   blocks 0..1023:    LayerNorm of node_i / node_j (4 rows/block, wave/row)
//   block 1024:        fold LN gamma into pair->head weights (MFMA B-frags)
//                      + AB[16] via LDS-parallel reduce
//   blocks 1025..1056: transpose {wq,wk,wv,wg} -> wT[m][col][c] bf16
//                      (q-scale folded into wT[0])
// grid: 1057 blocks, 256 threads
// ---------------------------------------------------------------------------
__global__ __launch_bounds__(256) void k_prep(
    const float* __restrict__ xi, const float* __restrict__ xj,
    const float* __restrict__ g_i, const float* __restrict__ b_i,
    const float* __restrict__ g_j, const float* __restrict__ b_j,
    const float* __restrict__ lng, const float* __restrict__ lnb,
    const float* __restrict__ wpb, const float* __restrict__ wpg,
    const float* __restrict__ wq, const float* __restrict__ wk,
    const float* __restrict__ wv, const float* __restrict__ wg,
    float* __restrict__ ni, float* __restrict__ nj,
    short* __restrict__ gwfB, float* __restrict__ AB,
    short* __restrict__ wT)
{
    const int bx  = blockIdx.x;
    const int tid = threadIdx.x;

    if (bx < 1024) {
        const int which = bx >> 9;
        const float* x  = which ? xj  : xi;
        const float* gg = which ? g_j : g_i;
        const float* bb = which ? b_j : b_i;
        float* o        = which ? nj  : ni;

        const int row  = (bx & 511) * 4 + (tid >> 6);
        const int lane = tid & 63;

        const float* xr = x + (size_t)row * C_ + lane * 8;
        float4 v0 = *(const float4*)xr;
        float4 v1 = *(const float4*)(xr + 4);

        float s  = v0.x + v0.y + v0.z + v0.w + v1.x + v1.y + v1.z + v1.w;
        float sq = v0.x*v0.x + v0.y*v0.y + v0.z*v0.z + v0.w*v0.w
                 + v1.x*v1.x + v1.y*v1.y + v1.z*v1.z + v1.w*v1.w;
#pragma unroll
        for (int m = 1; m <= 32; m <<= 1) {
            s  += __shfl_xor(s, m);
            sq += __shfl_xor(sq, m);
        }
        const float mean = s * (1.0f / C_);
        const float var  = sq * (1.0f / C_) - mean * mean;
        const float rstd = rsqrtf(var + EPS_);

        float4 ga  = *(const float4*)(gg + lane * 8);
        float4 gb  = *(const float4*)(gg + lane * 8 + 4);
        float4 ba  = *(const float4*)(bb + lane * 8);
        float4 bb4 = *(const float4*)(bb + lane * 8 + 4);

        float4 r0, r1;
        r0.x = (v0.x - mean) * rstd * ga.x + ba.x;
        r0.y = (v0.y - mean) * rstd * ga.y + ba.y;
        r0.z = (v0.z - mean) * rstd * ga.z + ba.z;
        r0.w = (v0.w - mean) * rstd * ga.w + ba.w;
        r1.x = (v1.x - mean) * rstd * gb.x + bb4.x;
        r1.y = (v1.y - mean) * rstd * gb.y + bb4.y;
        r1.z = (v1.z - mean) * rstd * gb.z + bb4.z;
        r1.w = (v1.w - mean) * rstd * gb.w + bb4.w;

        float* orow = o + (size_t)row * C_ + lane * 8;
        *(float4*)orow       = r0;
        *(float4*)(orow + 4) = r1;
    } else if (bx == 1024) {
        // ---- fold path ----
        __shared__ float sAB[P_ * 16];
        const int s = tid >> 6, lane = tid & 63;
        const int c = lane >> 4, n = lane & 15;
#pragma unroll
        for (int e = 0; e < 8; e++) {
            const int p = s * 32 + c * 8 + e;
            const float w = (n < 4) ? wpb[p * 4 + n]
                          : (n < 8) ? wpg[p * 4 + (n - 4)] : 0.0f;
            gwfB[(s * 64 + lane) * 8 + e] = f2bf(lng[p] * w);
        }
        if (tid < P_) {
            const int p = tid;
            const float g = lng[p], b = lnb[p];
#pragma unroll
            for (int h = 0; h < 4; h++) {
                const float wb = wpb[p * 4 + h], wgv = wpg[p * 4 + h];
                sAB[p * 16 + h]      = g * wb;
                sAB[p * 16 + 4 + h]  = g * wgv;
                sAB[p * 16 + 8 + h]  = b * wb;
                sAB[p * 16 + 12 + h] = b * wgv;
            }
        }
        __syncthreads();
        if (tid < 16) {
            float a = 0.0f;
            for (int p = 0; p < P_; p++) a += sAB[p * 16 + tid];
            AB[tid] = a;
        }
    } else {
        // ---- weight transpose: wT[m][col][c] (bf16) ----
        const int bx2 = bx - 1025;          // 0..31
        const int m  = bx2 >> 3, cg = bx2 & 7;
        const float* W = (m == 0) ? wq : (m == 1) ? wk : (m == 2) ? wv : wg;
        const float scale = (m == 0) ? QSCALE_ : 1.0f;
        const int col = cg * 16 + (tid & 15);
        const int c0  = (tid >> 4) * 32;
        short* dst = wT + m * 65536 + col * 512 + c0;
#pragma unroll
        for (int c4 = 0; c4 < 8; c4++) {
            s16x4 pk;
#pragma unroll
            for (int u = 0; u < 4; u++)
                pk[u] = f2bf(W[(size_t)(c0 + c4 * 4 + u) * HD_ + col] * scale);
            *(s16x4*)(dst + c4 * 4) = pk;
        }
    }
}

// ---------------------------------------------------------------------------
// pair-tile load / compute helpers (registers only; fully inlined)
// ---------------------------------------------------------------------------
__device__ __forceinline__ void pb_load(
    f32x4 (&xa)[4], f32x4 (&xb)[4], float& pm, int tile,
    const float* __restrict__ pair, const int* __restrict__ pmask,
    int r, int c)
{
    const float* xp = pair + ((size_t)tile * 16 + r) * P_ + c * 8;
#pragma unroll
    for (int s = 0; s < 4; s++) {
        xa[s] = *(const f32x4*)(xp + s * 32);
        xb[s] = *(const f32x4*)(xp + s * 32 + 4);
    }
    pm = (float)pmask[tile * 16 + r];
}

__device__ __forceinline__ void pb_compute(
    const f32x4 (&xa)[4], const f32x4 (&xb)[4], float pm, int tile,
    const bf16x8 (&bfrag)[4], float Al, float Ag, float Bl, float Bg,
    float* __restrict__ bias, int r, int c)
{
    f32x4 acc = {0.0f, 0.0f, 0.0f, 0.0f};
    float sum = 0.0f, sq = 0.0f;
#pragma unroll
    for (int s = 0; s < 4; s++) {
        const float e0 = xa[s].x, e1 = xa[s].y, e2 = xa[s].z, e3 = xa[s].w;
        const float e4 = xb[s].x, e5 = xb[s].y, e6 = xb[s].z, e7 = xb[s].w;
        sum += e0 + e1 + e2 + e3 + e4 + e5 + e6 + e7;
        sq = fmaf(e0, e0, sq); sq = fmaf(e1, e1, sq);
        sq = fmaf(e2, e2, sq); sq = fmaf(e3, e3, sq);
        sq = fmaf(e4, e4, sq); sq = fmaf(e5, e5, sq);
        sq = fmaf(e6, e6, sq); sq = fmaf(e7, e7, sq);
        bf16x8 afrag;
        afrag[0] = f2bf(e0); afrag[1] = f2bf(e1);
        afrag[2] = f2bf(e2); afrag[3] = f2bf(e3);
        afrag[4] = f2bf(e4); afrag[5] = f2bf(e5);
        afrag[6] = f2bf(e6); afrag[7] = f2bf(e7);
        acc = __builtin_amdgcn_mfma_f32_16x16x32_bf16(afrag, bfrag[s], acc, 0, 0, 0);
    }

    sum += __shfl_xor(sum, 16); sum += __shfl_xor(sum, 32);
    sq  += __shfl_xor(sq, 16);  sq  += __shfl_xor(sq, 32);
    const float mean = sum * (1.0f / P_);
    const float rstd = rsqrtf(sq * (1.0f / P_) - mean * mean + EPS_);
    const float mr   = mean * rstd;
    const float mb   = INF_ * (pm - 1.0f);

    const int base = tile * 16;
    const int j0 = base & (J_ - 1);
    const int i  = (base >> 9) & (I_ - 1);
    const int b  = base >> 18;
    const int n4 = r & 3;
    float* obase = bias + (((size_t)(b * H_ + n4) * I_ + i) << 9) + j0;

#pragma unroll
    for (int reg = 0; reg < 4; reg++) {
        const int rr = c * 4 + reg;
        const float rstd_r = __shfl(rstd, rr);
        const float mr_r   = __shfl(mr, rr);
        const float mb_r   = __shfl(mb, rr);
        const float Sg     = __shfl(acc[reg], (r & 63) + 4);
        if (r < 4) {
            const float left = fmaf(rstd_r, acc[reg], fmaf(-mr_r, Al, Bl));
            const float glog = fmaf(rstd_r, Sg,       fmaf(-mr_r, Ag, Bg));
            const float val  = left * (1.0f / (1.0f + __expf(-glog))) + mb_r;
            obase[rr] = val;
        }
    }
}

// ---------------------------------------------------------------------------
// K2: fused pair-bias (persistent, 2-deep prefetch) + projections.
//   blocks [0, PB_BLOCKS):        pair path, 8 tiles/wave, double-buffered regs
//   blocks [PB_BLOCKS, +128):     q/k/v/g projections via MFMA (m = idx>>5)
// grid: PB_BLOCKS + 128, block: 256
// ---------------------------------------------------------------------------
__global__ __launch_bounds__(256, 4) void k_fused(
    const float* __restrict__ pair, const int* __restrict__ pmask,
    const short* __restrict__ gwfB, const float* __restrict__ AB,
    float* __restrict__ bias,
    const float* __restrict__ ni, const float* __restrict__ nj,
    const short* __restrict__ wT, const float* __restrict__ bg,
    short* __restrict__ q_bf, short* __restrict__ k_bf,
    short* __restrict__ vT_bf, float* __restrict__ g_ws)
{
    const int lane = threadIdx.x & 63;
    const int wid  = threadIdx.x >> 6;
    const int r    = lane & 15;
    const int c    = lane >> 4;

    if (blockIdx.x < PB_BLOCKS) {
        // ================= pair path =================
        const int wave = blockIdx.x * 4 + wid;

        bf16x8 bfrag[4];
#pragma unroll
        for (int s = 0; s < 4; s++)
            bfrag[s] = *(const bf16x8*)(gwfB + (s * 64 + lane) * 8);
        const int n4 = r & 3;
        const float Al = AB[n4], Ag = AB[4 + n4];
        const float Bl = AB[8 + n4], Bg = AB[12 + n4];

        f32x4 xa0[4], xb0[4], xa1[4], xb1[4];
        float pm0, pm1;

        pb_load(xa0, xb0, pm0, wave, pair, pmask, r, c);
#pragma unroll
        for (int it = 0; it < PB_ITERS; it += 2) {
            const int tA = wave + it * PB_WAVES;
            const int tB = tA + PB_WAVES;
            pb_load(xa1, xb1, pm1, tB, pair, pmask, r, c);
            pb_compute(xa0, xb0, pm0, tA, bfrag, Al, Ag, Bl, Bg, bias, r, c);
            if (it + 2 < PB_ITERS)
                pb_load(xa0, xb0, pm0, tA + 2 * PB_WAVES, pair, pmask, r, c);
            pb_compute(xa1, xb1, pm1, tB, bfrag, Al, Ag, Bl, Bg, bias, r, c);
        }
    } else {
        // ================= projection path =================
        const int px = blockIdx.x - PB_BLOCKS;     // 0..127
        const int m  = px >> 5;                    // 0..3 : q,k,v,g
        const int i0 = (px & 31) * 64 + wid * 16;  // row in [0, B*I)
        const float* src = (m == 0 || m == 3) ? ni : nj;
        const short* wbase = wT + m * 65536 + c * 8;

        f32x4 acc[8];
#pragma unroll
        for (int nt = 0; nt < 8; nt++) acc[nt] = (f32x4){0.0f, 0.0f, 0.0f, 0.0f};

        const float* arow = src + (size_t)(i0 + r) * C_ + c * 8;
#pragma unroll 4
        for (int kk = 0; kk < 16; kk++) {
            const f32x4 a0 = *(const f32x4*)(arow + kk * 32);
            const f32x4 a1 = *(const f32x4*)(arow + kk * 32 + 4);
            bf16x8 af;
            af[0] = f2bf(a0.x); af[1] = f2bf(a0.y); af[2] = f2bf(a0.z); af[3] = f2bf(a0.w);
            af[4] = f2bf(a1.x); af[5] = f2bf(a1.y); af[6] = f2bf(a1.z); af[7] = f2bf(a1.w);
#pragma unroll
            for (int nt = 0; nt < 8; nt++) {
                const bf16x8 bf = *(const bf16x8*)(wbase + (nt * 16 + r) * 512 + kk * 32);
                acc[nt] = __builtin_amdgcn_mfma_f32_16x16x32_bf16(af, bf, acc[nt], 0, 0, 0);
            }
        }

        const int b  = i0 >> 9;
        const int il = i0 & 511;
#pragma unroll
        for (int nt = 0; nt < 8; nt++) {
            const int col = nt * 16 + r;
            if (m == 3) {
                const float bgc = bg[col];
#pragma unroll
                for (int reg = 0; reg < 4; reg++) {
                    const int row = i0 + c * 4 + reg;
                    g_ws[(size_t)row * HD_ + col] =
                        1.0f / (1.0f + __expf(-(acc[nt][reg] + bgc)));
                }
            } else if (m == 2) {
                const int h = col >> 5, d = col & 31;
                const int j = il + c * 4;
                s16x4 pk;
                pk[0] = f2bf(acc[nt][0]); pk[1] = f2bf(acc[nt][1]);
                pk[2] = f2bf(acc[nt][2]); pk[3] = f2bf(acc[nt][3]);
                *(s16x4*)(vT_bf + ((size_t)(b * H_ + h) * D_ + d) * J_ + j) = pk;
            } else {
                short* dst = (m == 0) ? q_bf : k_bf;
                const int h = col >> 5, d = col & 31;
#pragma unroll
                for (int reg = 0; reg < 4; reg++) {
                    const int i = il + c * 4 + reg;
                    dst[((size_t)(b * H_ + h) * 512 + i) * D_ + d] = f2bf(acc[nt][reg]);
                }
            }
        }
    }
}

// ---------------------------------------------------------------------------
// K4: attention via MFMA. Block = (bh, 16-i tile), 4 waves.
// grid: (I/16, B*H), block: 256
// ---------------------------------------------------------------------------
__global__ __launch_bounds__(256) void k_attn(
    const short* __restrict__ q_bf, const short* __restrict__ k_bf,
    const short* __restrict__ vT_bf, const float* __restrict__ bias,
    float* __restrict__ o_ws)
{
    __shared__ short s_p[16 * 520];       // P bf16, pitch 520
    __shared__ float s_red[2 * 4 * 16];   // [max|sum][wave][row]
    __shared__ float s_o[2 * 16 * 34];    // [j-half][row][d] padded

    const int tid  = threadIdx.x;
    const int w    = tid >> 6;
    const int lane = tid & 63;
    const int r    = lane & 15;
    const int c    = lane >> 4;
    const int bh   = blockIdx.y;
    const int i0   = blockIdx.x * 16;

    // ---- QK^T with bias C-init ----
    const bf16x8 qf = *(const bf16x8*)(q_bf + ((size_t)bh * I_ + i0 + r) * D_ + c * 8);
    f32x4 acc[8];
#pragma unroll
    for (int t = 0; t < 8; t++) {
        const int jt = w * 8 + t;
        const float* bp = bias + ((size_t)bh * I_ + i0 + c * 4) * J_ + jt * 16 + r;
        f32x4 ci;
        ci[0] = bp[0]; ci[1] = bp[J_]; ci[2] = bp[2 * J_]; ci[3] = bp[3 * J_];
        const bf16x8 kf = *(const bf16x8*)(k_bf + ((size_t)bh * J_ + jt * 16 + r) * D_ + c * 8);
        acc[t] = __builtin_amdgcn_mfma_f32_16x16x32_bf16(qf, kf, ci, 0, 0, 0);
    }

    // ---- row max (this wave's j-range) ----
    float mx[4];
#pragma unroll
    for (int reg = 0; reg < 4; reg++) {
        float m0 = acc[0][reg];
#pragma unroll
        for (int t = 1; t < 8; t++) m0 = fmaxf(m0, acc[t][reg]);
        mx[reg] = m0;
    }
#pragma unroll
    for (int mm = 1; mm < 16; mm <<= 1) {
#pragma unroll
        for (int reg = 0; reg < 4; reg++)
            mx[reg] = fmaxf(mx[reg], __shfl_xor(mx[reg], mm));
    }
    if (r < 4) {
        const float v = (r == 0) ? mx[0] : (r == 1) ? mx[1] : (r == 2) ? mx[2] : mx[3];
        s_red[w * 16 + c * 4 + r] = v;
    }
    __syncthreads();

    float M[4];
#pragma unroll
    for (int reg = 0; reg < 4; reg++) {
        const int row = c * 4 + reg;
        M[reg] = fmaxf(fmaxf(s_red[row], s_red[16 + row]),
                       fmaxf(s_red[32 + row], s_red[48 + row]));
    }

    // ---- p = exp(logit - M), store bf16 to LDS, accumulate sums ----
    float sm[4] = {0.0f, 0.0f, 0.0f, 0.0f};
#pragma unroll
    for (int t = 0; t < 8; t++) {
        const int j = (w * 8 + t) * 16 + r;
#pragma unroll
        for (int reg = 0; reg < 4; reg++) {
            const float p = __expf(acc[t][reg] - M[reg]);
            sm[reg] += p;
            s_p[(c * 4 + reg) * 520 + j] = f2bf(p);
        }
    }
#pragma unroll
    for (int mm = 1; mm < 16; mm <<= 1) {
#pragma unroll
        for (int reg = 0; reg < 4; reg++)
            sm[reg] += __shfl_xor(sm[reg], mm);
    }
    if (r < 4) {
        const float v = (r == 0) ? sm[0] : (r == 1) ? sm[1] : (r == 2) ? sm[2] : sm[3];
        s_red[64 + w * 16 + c * 4 + r] = v;
    }
    __syncthreads();

    // ---- PV: wave = (d-tile, j-half) ----
    const int nt = w & 1, jh = w >> 1;
    f32x4 oacc = {0.0f, 0.0f, 0.0f, 0.0f};
    const short* vrow = vT_bf + ((size_t)bh * D_ + nt * 16 + r) * J_ + c * 8;
#pragma unroll
    for (int kk8 = 0; kk8 < 8; kk8++) {
        const int kk = jh * 8 + kk8;
        const bf16x8 pf = *(const bf16x8*)(s_p + r * 520 + kk * 32 + c * 8);
        const bf16x8 vf = *(const bf16x8*)(vrow + kk * 32);
        oacc = __builtin_amdgcn_mfma_f32_16x16x32_bf16(pf, vf, oacc, 0, 0, 0);
    }
#pragma unroll
    for (int reg = 0; reg < 4; reg++)
        s_o[jh * 544 + (c * 4 + reg) * 34 + nt * 16 + r] = oacc[reg];
    __syncthreads();

    // ---- combine halves, normalize, write ----
    const int il = tid >> 4, dd = (tid & 15) * 2;
    const float den = s_red[64 + il] + s_red[64 + 16 + il]
                    + s_red[64 + 32 + il] + s_red[64 + 48 + il];
    const float rs = 1.0f / den;
    const float v0 = (s_o[il * 34 + dd]     + s_o[544 + il * 34 + dd])     * rs;
    const float v1 = (s_o[il * 34 + dd + 1] + s_o[544 + il * 34 + dd + 1]) * rs;
    const int b = bh >> 2, h = bh & 3;
    float* op = o_ws + ((size_t)(b * I_ + i0 + il)) * HD_ + h * D_ + dd;
    op[0] = v0; op[1] = v1;
}

// ---------------------------------------------------------------------------
// K5: out = ni + ((o*g) @ wo + bo) * node_mask. 4-row tiles.
// grid: (B*I/4), block: 256
// ---------------------------------------------------------------------------
__global__ __launch_bounds__(256) void k_out(
    const float* __restrict__ o_ws, const float* __restrict__ g_ws,
    const float* __restrict__ ni, const float* __restrict__ wo,
    const float* __restrict__ bo, const int* __restrict__ nmask,
    float* __restrict__ out)
{
    __shared__ float s_og[4 * 128];
    const int tid  = threadIdx.x;
    const int base = blockIdx.x * 4;

#pragma unroll
    for (int rep = 0; rep < 2; rep++) {
        const int flat = rep * 256 + tid;
        s_og[flat] = o_ws[(size_t)base * HD_ + flat] * g_ws[(size_t)base * HD_ + flat];
    }
    __syncthreads();

    const int c0 = tid * 2;
    float a0[4] = {0, 0, 0, 0};
    float a1[4] = {0, 0, 0, 0};

#pragma unroll 4
    for (int hd = 0; hd < HD_; hd++) {
        const float2 wv = *(const float2*)(wo + hd * C_ + c0);
#pragma unroll
        for (int r = 0; r < 4; r++) {
            const float v = s_og[r * 128 + hd];
            a0[r] += v * wv.x;
            a1[r] += v * wv.y;
        }
    }

    const float b0v = bo[c0], b1v = bo[c0 + 1];
#pragma unroll
    for (int r = 0; r < 4; r++) {
        const int row = base + r;
        const float mk = (float)nmask[row];
        const size_t off = (size_t)row * C_ + c0;
        out[off]     = ni[off]     + (a0[r] + b0v) * mk;
        out[off + 1] = ni[off + 1] + (a1[r] + b1v) * mk;
    }
}

// ---------------------------------------------------------------------------
extern "C" void kernel_launch(void* const* d_in, const int* in_sizes, int n_in,
                              void* d_out, int out_size, void* d_ws, size_t ws_size,
                              hipStream_t stream)
{
    const float* node_i = (const float*)d_in[0];
    const float* node_j = (const float*)d_in[1];
    const float* pair   = (const float*)d_in[2];
    const int*   pmask  = (const int*)d_in[3];
    const int*   nmask  = (const int*)d_in[4];
    const float* ln_i_g = (const float*)d_in[5];
    const float* ln_i_b = (const float*)d_in[6];
    const float* ln_j_g = (const float*)d_in[7];
    const float* ln_j_b = (const float*)d_in[8];
    const float* ln_p_g = (const float*)d_in[9];
    const float* ln_p_b = (const float*)d_in[10];
    const float* w_pb   = (const float*)d_in[11];
    const float* w_pg   = (const float*)d_in[12];
    const float* wq     = (const float*)d_in[13];
    const float* wk     = (const float*)d_in[14];
    const float* wv     = (const float*)d_in[15];
    const float* wg     = (const float*)d_in[16];
    const float* bg     = (const float*)d_in[17];
    const float* wo     = (const float*)d_in[18];
    const float* bo     = (const float*)d_in[19];

    float* out = (float*)d_out;
    float* ws  = (float*)d_ws;

    float* ni    = ws;                        // 1,048,576 floats
    float* nj    = ws + 1048576;              // 1,048,576
    float* bias  = ws + 2097152;              // 4,194,304  [B,H,I,J]
    float* g_ws  = ws + 6291456;              // 262,144    [B*I][HD]
    float* o_ws  = ws + 6553600;              // 262,144    [B*I][HD]
    short* q_bf  = (short*)(ws + 6815744);    // 262,144 shorts [BH][I][D]
    short* k_bf  = (short*)(ws + 6946816);    // 262,144 shorts [BH][J][D]
    short* vT_bf = (short*)(ws + 7077888);    // 262,144 shorts [BH][D][J]
    short* wT    = (short*)(ws + 7208960);    // 262,144 shorts [4][128][512]
    short* gwfB  = (short*)(ws + 7340032);    // 2,048 shorts
    float* AB    = ws + 7341056;              // 16 floats

    k_prep<<<dim3(1057), 256, 0, stream>>>(node_i, node_j, ln_i_g, ln_i_b,
                                           ln_j_g, ln_j_b, ln_p_g, ln_p_b,
                                           w_pb, w_pg, wq, wk, wv, wg,
                                           ni, nj, gwfB, AB, wT);
    k_fused<<<dim3(PB_BLOCKS + 128), 256, 0, stream>>>(
        pair, pmask, gwfB, AB, bias, ni, nj, wT, bg,
        q_bf, k_bf, vT_bf, g_ws);
    k_attn<<<dim3(32, 16), 256, 0, stream>>>(q_bf, k_bf, vT_bf, bias, o_ws);
    k_out<<<dim3(512), 256, 0, stream>>>(o_ws, g_ws, ni, wo, bo, nmask, out);
}